// Round 1
// baseline (3340.244 us; speedup 1.0000x reference)
//
#include <hip/hip_runtime.h>
#include <math.h>

// ---------------------------------------------------------------------------
// GCN policy forward for MI355X. Round 1: fp32 correctness-first.
//
// Pipeline (per kernel_launch):
//   pv0 = embed(pivot)  ch0 = embed(children)
//   vc:  RW=ch0@wl+bl, LW=pv0@wr, S=scatter_relu((RW[dst]+LW[src])*sf),
//        agg=(S/cnt)@wf+bf[cnt>0], ch1=relu([agg*sp,ch0]@wo1+bo1)@wo2+bo2
//   cv:  same with reversed edges onto pivot
//   out = sigmoid(relu(pv1@ow1+ob1)@ow2+ob2)
// ---------------------------------------------------------------------------

// Generic fused linear: out[M,128] = act( A @ W + bias ), where A is
// optionally: prenormed ((a+shift)*scale), row-divided (mean), scaled (sp),
// and optionally concatenated with A2 at column Ksplit (both stride-128).
__global__ __launch_bounds__(256) void gemm_fused(
    const float* __restrict__ A1, const float* __restrict__ A2,
    const float* __restrict__ W, const float* __restrict__ bias,
    const float* __restrict__ shift, const float* __restrict__ scale,
    const float* __restrict__ rowdiv, const float* __restrict__ gate,
    const float* __restrict__ a1scale_p,
    float* __restrict__ out,
    int M, int K, int Ksplit, int relu)
{
    __shared__ float As[64][64];
    __shared__ float Ws[64][128];
    const int tid = threadIdx.x;
    const int tx = tid & 31, ty = tid >> 5;
    const int m0 = blockIdx.x * 64;
    const float a1s = a1scale_p ? *a1scale_p : 1.0f;

    float acc[8][4];
#pragma unroll
    for (int r = 0; r < 8; ++r)
#pragma unroll
        for (int c = 0; c < 4; ++c) acc[r][c] = 0.f;

    for (int kk = 0; kk < K; kk += 64) {
        // stage A tile [64 rows][64 k]
#pragma unroll
        for (int j = 0; j < 16; ++j) {
            int idx = j * 256 + tid;
            int r = idx >> 6, cc = idx & 63;
            int grow = m0 + r, gk = kk + cc;
            float v = 0.f;
            if (grow < M && gk < K) {
                if (gk < Ksplit) {
                    v = A1[(size_t)grow * Ksplit + gk];
                    if (shift) v = (v + shift[gk]) * scale[gk];
                    if (rowdiv) v *= 1.0f / fmaxf(rowdiv[grow], 1.0f);
                    v *= a1s;
                } else {
                    v = A2[(size_t)grow * 128 + (gk - Ksplit)];
                }
            }
            As[r][cc] = v;
        }
        // stage W tile [64 k][128 n] (float4)
#pragma unroll
        for (int j = 0; j < 8; ++j) {
            int slot = j * 256 + tid;
            int r = slot >> 5, c4 = slot & 31;
            int gk = kk + r;
            float4 v = make_float4(0.f, 0.f, 0.f, 0.f);
            if (gk < K) v = *(const float4*)&W[(size_t)gk * 128 + c4 * 4];
            *(float4*)&Ws[r][c4 * 4] = v;
        }
        __syncthreads();
#pragma unroll 4
        for (int k = 0; k < 64; ++k) {
            float4 w = *(const float4*)&Ws[k][tx * 4];
#pragma unroll
            for (int r = 0; r < 8; ++r) {
                float a = As[ty * 8 + r][k];
                acc[r][0] += a * w.x;
                acc[r][1] += a * w.y;
                acc[r][2] += a * w.z;
                acc[r][3] += a * w.w;
            }
        }
        __syncthreads();
    }
#pragma unroll
    for (int r = 0; r < 8; ++r) {
        int grow = m0 + ty * 8 + r;
        if (grow >= M) continue;
        float g = 1.f;
        if (gate) g = (gate[grow] > 0.f) ? 1.f : 0.f;
        float4 o;
        float b0 = 0.f, b1 = 0.f, b2v = 0.f, b3 = 0.f;
        if (bias) {
            b0 = bias[tx * 4 + 0] * g;
            b1 = bias[tx * 4 + 1] * g;
            b2v = bias[tx * 4 + 2] * g;
            b3 = bias[tx * 4 + 3] * g;
        }
        o.x = acc[r][0] + b0;
        o.y = acc[r][1] + b1;
        o.z = acc[r][2] + b2v;
        o.w = acc[r][3] + b3;
        if (relu) {
            o.x = fmaxf(o.x, 0.f); o.y = fmaxf(o.y, 0.f);
            o.z = fmaxf(o.z, 0.f); o.w = fmaxf(o.w, 0.f);
        }
        *(float4*)&out[(size_t)grow * 128 + tx * 4] = o;
    }
}

// Edge kernel: 32 lanes per edge, 4 dims/lane.
// S[idx_r[e]] += relu((RW[idx_r[e]] + LW[idx_l[e]]) * sf);  cnt[idx_r[e]] += 1
__global__ __launch_bounds__(256) void edge_scatter(
    const int* __restrict__ idx_r, const int* __restrict__ idx_l,
    const float* __restrict__ RW, const float* __restrict__ LW,
    float* __restrict__ S, float* __restrict__ cnt,
    const float* __restrict__ sf_p, int E)
{
    int t = blockIdx.x * 256 + threadIdx.x;
    int e = t >> 5;
    if (e >= E) return;
    int lane = t & 31;
    const float sf = *sf_p;
    int nr = idx_r[e], nl = idx_l[e];
    const float4 a = *(const float4*)&RW[(size_t)nr * 128 + lane * 4];
    const float4 b = *(const float4*)&LW[(size_t)nl * 128 + lane * 4];
    float4 v;
    v.x = fmaxf((a.x + b.x) * sf, 0.f);
    v.y = fmaxf((a.y + b.y) * sf, 0.f);
    v.z = fmaxf((a.z + b.z) * sf, 0.f);
    v.w = fmaxf((a.w + b.w) * sf, 0.f);
    float* dp = &S[(size_t)nr * 128 + lane * 4];
    atomicAdd(dp + 0, v.x);
    atomicAdd(dp + 1, v.y);
    atomicAdd(dp + 2, v.z);
    atomicAdd(dp + 3, v.w);
    if (lane == 0) atomicAdd(&cnt[nr], 1.0f);
}

// Head: out[row,0..1] = sigmoid(T[row] @ w2 + b2); one wave per row.
__global__ __launch_bounds__(256) void final_head(
    const float* __restrict__ T, const float* __restrict__ w2,
    const float* __restrict__ b2, float* __restrict__ out, int M)
{
    int wid = threadIdx.x >> 6, lane = threadIdx.x & 63;
    int row = blockIdx.x * 4 + wid;
    if (row >= M) return;
    float x0 = T[(size_t)row * 128 + lane];
    float x1 = T[(size_t)row * 128 + 64 + lane];
    float p0 = x0 * w2[lane * 2 + 0] + x1 * w2[(64 + lane) * 2 + 0];
    float p1 = x0 * w2[lane * 2 + 1] + x1 * w2[(64 + lane) * 2 + 1];
#pragma unroll
    for (int o = 32; o > 0; o >>= 1) {
        p0 += __shfl_xor(p0, o);
        p1 += __shfl_xor(p1, o);
    }
    if (lane == 0) {
        out[(size_t)row * 2 + 0] = 1.f / (1.f + expf(-(p0 + b2[0])));
        out[(size_t)row * 2 + 1] = 1.f / (1.f + expf(-(p1 + b2[1])));
    }
}

extern "C" void kernel_launch(void* const* d_in, const int* in_sizes, int n_in,
                              void* d_out, int out_size, void* d_ws, size_t ws_size,
                              hipStream_t stream)
{
    const float* pivot = (const float*)d_in[0];
    const float* child = (const float*)d_in[1];
    const int* edges = (const int*)d_in[2];
    const int F = in_sizes[3];           // 69
    const int NP = in_sizes[0] / F;
    const int NC = in_sizes[1] / F;
    const int E = in_sizes[2] / 2;
    const int* src = edges;
    const int* dst = edges + E;

    const float *pe_shift = (const float*)d_in[3], *pe_scale = (const float*)d_in[4],
                *pe_w1 = (const float*)d_in[5], *pe_b1 = (const float*)d_in[6],
                *pe_w2 = (const float*)d_in[7], *pe_b2 = (const float*)d_in[8];
    const float *ce_shift = (const float*)d_in[9], *ce_scale = (const float*)d_in[10],
                *ce_w1 = (const float*)d_in[11], *ce_b1 = (const float*)d_in[12],
                *ce_w2 = (const float*)d_in[13], *ce_b2 = (const float*)d_in[14];
    const float *vc_wl = (const float*)d_in[15], *vc_bl = (const float*)d_in[16],
                *vc_wr = (const float*)d_in[17], *vc_sf = (const float*)d_in[18],
                *vc_wf = (const float*)d_in[19], *vc_bf = (const float*)d_in[20],
                *vc_sp = (const float*)d_in[21], *vc_wo1 = (const float*)d_in[22],
                *vc_bo1 = (const float*)d_in[23], *vc_wo2 = (const float*)d_in[24],
                *vc_bo2 = (const float*)d_in[25];
    const float *cv_wl = (const float*)d_in[26], *cv_bl = (const float*)d_in[27],
                *cv_wr = (const float*)d_in[28], *cv_sf = (const float*)d_in[29],
                *cv_wf = (const float*)d_in[30], *cv_bf = (const float*)d_in[31],
                *cv_sp = (const float*)d_in[32], *cv_wo1 = (const float*)d_in[33],
                *cv_bo1 = (const float*)d_in[34], *cv_wo2 = (const float*)d_in[35],
                *cv_bo2 = (const float*)d_in[36];
    const float *out_w1 = (const float*)d_in[37], *out_b1 = (const float*)d_in[38],
                *out_w2 = (const float*)d_in[39], *out_b2 = (const float*)d_in[40];

    const size_t NP128 = (size_t)NP * 128, NC128 = (size_t)NC * 128;
    float* ws = (float*)d_ws;
    float* W0 = ws;               // [NP,128] pv0
    float* W1 = W0 + NP128;       // [NC,128] ch0 -> S_p -> pv1
    float* W2 = W1 + NC128;       // [NC,128] scratch
    float* W3 = W2 + NC128;       // [NC,128] scratch
    float* W4 = W3 + NC128;       // [NC,128] S_c -> ch1
    float* W5 = W4 + NC128;       // [NC] cnt

    auto gemm = [&](const float* A1, const float* A2, const float* Wp, const float* b,
                    const float* sh, const float* sc, const float* rd, const float* gt,
                    const float* a1s, float* o, int M, int K, int Ksplit, int relu) {
        hipLaunchKernelGGL(gemm_fused, dim3((M + 63) / 64), dim3(256), 0, stream,
                           A1, A2, Wp, b, sh, sc, rd, gt, a1s, o, M, K, Ksplit, relu);
    };

    // --- embeddings ---
    gemm(pivot, nullptr, pe_w1, pe_b1, pe_shift, pe_scale, nullptr, nullptr, nullptr,
         W2, NP, F, F, 1);
    gemm(W2, nullptr, pe_w2, pe_b2, nullptr, nullptr, nullptr, nullptr, nullptr,
         W0, NP, 128, 128, 1);                                   // pv0
    gemm(child, nullptr, ce_w1, ce_b1, ce_shift, ce_scale, nullptr, nullptr, nullptr,
         W2, NC, F, F, 1);
    gemm(W2, nullptr, ce_w2, ce_b2, nullptr, nullptr, nullptr, nullptr, nullptr,
         W1, NC, 128, 128, 1);                                   // ch0

    // --- conv v->c (aggregate to children) ---
    gemm(W1, nullptr, vc_wl, vc_bl, nullptr, nullptr, nullptr, nullptr, nullptr,
         W2, NC, 128, 128, 0);                                   // RW = ch0@wl+bl
    gemm(W0, nullptr, vc_wr, nullptr, nullptr, nullptr, nullptr, nullptr, nullptr,
         W3, NP, 128, 128, 0);                                   // LW = pv0@wr
    hipMemsetAsync(W4, 0, NC128 * sizeof(float), stream);
    hipMemsetAsync(W5, 0, (size_t)NC * sizeof(float), stream);
    {
        long long tt = (long long)E * 32;
        hipLaunchKernelGGL(edge_scatter, dim3((tt + 255) / 256), dim3(256), 0, stream,
                           dst, src, W2, W3, W4, W5, vc_sf, E);
    }
    gemm(W4, nullptr, vc_wf, vc_bf, nullptr, nullptr, W5, W5, nullptr,
         W3, NC, 128, 128, 0);                                   // agg_c
    gemm(W3, W1, vc_wo1, vc_bo1, nullptr, nullptr, nullptr, nullptr, vc_sp,
         W2, NC, 256, 128, 1);                                   // relu(h@wo1+bo1)
    gemm(W2, nullptr, vc_wo2, vc_bo2, nullptr, nullptr, nullptr, nullptr, nullptr,
         W4, NC, 128, 128, 0);                                   // ch1

    // --- conv c->v (aggregate to pivot, reversed edges) ---
    gemm(W0, nullptr, cv_wl, cv_bl, nullptr, nullptr, nullptr, nullptr, nullptr,
         W2, NP, 128, 128, 0);                                   // RW_p = pv0@wl+bl
    gemm(W4, nullptr, cv_wr, nullptr, nullptr, nullptr, nullptr, nullptr, nullptr,
         W3, NC, 128, 128, 0);                                   // LW_c = ch1@wr
    hipMemsetAsync(W1, 0, NP128 * sizeof(float), stream);
    hipMemsetAsync(W5, 0, (size_t)NP * sizeof(float), stream);
    {
        long long tt = (long long)E * 32;
        hipLaunchKernelGGL(edge_scatter, dim3((tt + 255) / 256), dim3(256), 0, stream,
                           src, dst, W2, W3, W1, W5, cv_sf, E);
    }
    gemm(W1, nullptr, cv_wf, cv_bf, nullptr, nullptr, W5, W5, nullptr,
         W2, NP, 128, 128, 0);                                   // agg_p
    gemm(W2, W0, cv_wo1, cv_bo1, nullptr, nullptr, nullptr, nullptr, cv_sp,
         W3, NP, 256, 128, 1);
    gemm(W3, nullptr, cv_wo2, cv_bo2, nullptr, nullptr, nullptr, nullptr, nullptr,
         W1, NP, 128, 128, 0);                                   // pv1

    // --- head ---
    gemm(W1, nullptr, out_w1, out_b1, nullptr, nullptr, nullptr, nullptr, nullptr,
         W2, NP, 128, 128, 1);
    hipLaunchKernelGGL(final_head, dim3((NP + 3) / 4), dim3(256), 0, stream,
                       W2, out_w2, out_b2, (float*)d_out, NP);
}

// Round 2
// 1454.095 us; speedup vs baseline: 2.2971x; 2.2971x over previous
//
#include <hip/hip_runtime.h>
#include <math.h>

// ---------------------------------------------------------------------------
// GCN policy forward, round 2: atomic scatter -> on-device CSR + gather.
//   - Build adjacency (per launch): histogram (int atomics), offsets via
//     wave-aggregated atomic (regions contiguous, order irrelevant), scatter.
//   - Aggregation: 32 lanes per destination node, gather LW[src] rows,
//     relu-accumulate in registers, write mean once. No float atomics.
// GEMMs unchanged from round 1 (fp32 SMEM-tiled); bf16 MFMA is next round.
// ---------------------------------------------------------------------------

__global__ __launch_bounds__(256) void gemm_fused(
    const float* __restrict__ A1, const float* __restrict__ A2,
    const float* __restrict__ W, const float* __restrict__ bias,
    const float* __restrict__ shift, const float* __restrict__ scale,
    const float* __restrict__ gate,
    const float* __restrict__ a1scale_p,
    float* __restrict__ out,
    int M, int K, int Ksplit, int relu)
{
    __shared__ float As[64][64];
    __shared__ float Ws[64][128];
    const int tid = threadIdx.x;
    const int tx = tid & 31, ty = tid >> 5;
    const int m0 = blockIdx.x * 64;
    const float a1s = a1scale_p ? *a1scale_p : 1.0f;

    float acc[8][4];
#pragma unroll
    for (int r = 0; r < 8; ++r)
#pragma unroll
        for (int c = 0; c < 4; ++c) acc[r][c] = 0.f;

    for (int kk = 0; kk < K; kk += 64) {
#pragma unroll
        for (int j = 0; j < 16; ++j) {
            int idx = j * 256 + tid;
            int r = idx >> 6, cc = idx & 63;
            int grow = m0 + r, gk = kk + cc;
            float v = 0.f;
            if (grow < M && gk < K) {
                if (gk < Ksplit) {
                    v = A1[(size_t)grow * Ksplit + gk];
                    if (shift) v = (v + shift[gk]) * scale[gk];
                    v *= a1s;
                } else {
                    v = A2[(size_t)grow * 128 + (gk - Ksplit)];
                }
            }
            As[r][cc] = v;
        }
#pragma unroll
        for (int j = 0; j < 8; ++j) {
            int slot = j * 256 + tid;
            int r = slot >> 5, c4 = slot & 31;
            int gk = kk + r;
            float4 v = make_float4(0.f, 0.f, 0.f, 0.f);
            if (gk < K) v = *(const float4*)&W[(size_t)gk * 128 + c4 * 4];
            *(float4*)&Ws[r][c4 * 4] = v;
        }
        __syncthreads();
#pragma unroll 4
        for (int k = 0; k < 64; ++k) {
            float4 w = *(const float4*)&Ws[k][tx * 4];
#pragma unroll
            for (int r = 0; r < 8; ++r) {
                float a = As[ty * 8 + r][k];
                acc[r][0] += a * w.x;
                acc[r][1] += a * w.y;
                acc[r][2] += a * w.z;
                acc[r][3] += a * w.w;
            }
        }
        __syncthreads();
    }
#pragma unroll
    for (int r = 0; r < 8; ++r) {
        int grow = m0 + ty * 8 + r;
        if (grow >= M) continue;
        float g = 1.f;
        if (gate) g = (gate[grow] > 0.f) ? 1.f : 0.f;
        float4 o;
        float b0 = 0.f, b1 = 0.f, b2v = 0.f, b3 = 0.f;
        if (bias) {
            b0 = bias[tx * 4 + 0] * g;
            b1 = bias[tx * 4 + 1] * g;
            b2v = bias[tx * 4 + 2] * g;
            b3 = bias[tx * 4 + 3] * g;
        }
        o.x = acc[r][0] + b0;
        o.y = acc[r][1] + b1;
        o.z = acc[r][2] + b2v;
        o.w = acc[r][3] + b3;
        if (relu) {
            o.x = fmaxf(o.x, 0.f); o.y = fmaxf(o.y, 0.f);
            o.z = fmaxf(o.z, 0.f); o.w = fmaxf(o.w, 0.f);
        }
        *(float4*)&out[(size_t)grow * 128 + tx * 4] = o;
    }
}

// ---- CSR build ----
__global__ __launch_bounds__(256) void hist_kernel(
    const int* __restrict__ key, int* __restrict__ cnt, int E)
{
    int e = blockIdx.x * 256 + threadIdx.x;
    if (e < E) atomicAdd(&cnt[key[e]], 1);
}

// off[n] = exclusive running total; regions contiguous, node order arbitrary.
__global__ __launch_bounds__(256) void offsets_kernel(
    const int* __restrict__ cnt, int* __restrict__ off,
    int* __restrict__ total, int N)
{
    int n = blockIdx.x * 256 + threadIdx.x;
    int lane = threadIdx.x & 63;
    int v = (n < N) ? cnt[n] : 0;
    int incl = v;
#pragma unroll
    for (int d = 1; d < 64; d <<= 1) {
        int up = __shfl_up(incl, d);
        if (lane >= d) incl += up;
    }
    int wave_sum = __shfl(incl, 63);
    int base = 0;
    if (lane == 63) base = atomicAdd(total, wave_sum);
    base = __shfl(base, 63);
    if (n < N) off[n] = base + incl - v;
}

__global__ __launch_bounds__(256) void scatter_adj(
    const int* __restrict__ key, const int* __restrict__ val,
    const int* __restrict__ off, int* __restrict__ fill,
    int* __restrict__ adj, int E)
{
    int e = blockIdx.x * 256 + threadIdx.x;
    if (e < E) {
        int k = key[e];
        int p = off[k] + atomicAdd(&fill[k], 1);
        adj[p] = val[e];
    }
}

// ---- gather aggregation: Sdiv[n] = mean_e relu((RW[n]+LW[adj])*sf) ----
__global__ __launch_bounds__(256) void node_gather(
    const int* __restrict__ off, const int* __restrict__ cnt,
    const int* __restrict__ adj,
    const float* __restrict__ RW, const float* __restrict__ LW,
    float* __restrict__ Sdiv, float* __restrict__ cntf,
    const float* __restrict__ sf_p, int N)
{
    int t = blockIdx.x * 256 + threadIdx.x;
    int n = t >> 5;
    if (n >= N) return;
    int lane = t & 31;
    const float sf = *sf_p;
    int start = off[n], len = cnt[n];
    float4 rw = *(const float4*)&RW[(size_t)n * 128 + lane * 4];
    float4 acc = make_float4(0.f, 0.f, 0.f, 0.f);
    for (int i = 0; i < len; ++i) {
        int l = adj[start + i];
        float4 lw = *(const float4*)&LW[(size_t)l * 128 + lane * 4];
        acc.x += fmaxf((rw.x + lw.x) * sf, 0.f);
        acc.y += fmaxf((rw.y + lw.y) * sf, 0.f);
        acc.z += fmaxf((rw.z + lw.z) * sf, 0.f);
        acc.w += fmaxf((rw.w + lw.w) * sf, 0.f);
    }
    float inv = 1.f / fmaxf((float)len, 1.f);
    acc.x *= inv; acc.y *= inv; acc.z *= inv; acc.w *= inv;
    *(float4*)&Sdiv[(size_t)n * 128 + lane * 4] = acc;
    if (lane == 0) cntf[n] = (float)len;
}

__global__ __launch_bounds__(256) void final_head(
    const float* __restrict__ T, const float* __restrict__ w2,
    const float* __restrict__ b2, float* __restrict__ out, int M)
{
    int wid = threadIdx.x >> 6, lane = threadIdx.x & 63;
    int row = blockIdx.x * 4 + wid;
    if (row >= M) return;
    float x0 = T[(size_t)row * 128 + lane];
    float x1 = T[(size_t)row * 128 + 64 + lane];
    float p0 = x0 * w2[lane * 2 + 0] + x1 * w2[(64 + lane) * 2 + 0];
    float p1 = x0 * w2[lane * 2 + 1] + x1 * w2[(64 + lane) * 2 + 1];
#pragma unroll
    for (int o = 32; o > 0; o >>= 1) {
        p0 += __shfl_xor(p0, o);
        p1 += __shfl_xor(p1, o);
    }
    if (lane == 0) {
        out[(size_t)row * 2 + 0] = 1.f / (1.f + expf(-(p0 + b2[0])));
        out[(size_t)row * 2 + 1] = 1.f / (1.f + expf(-(p1 + b2[1])));
    }
}

extern "C" void kernel_launch(void* const* d_in, const int* in_sizes, int n_in,
                              void* d_out, int out_size, void* d_ws, size_t ws_size,
                              hipStream_t stream)
{
    const float* pivot = (const float*)d_in[0];
    const float* child = (const float*)d_in[1];
    const int* edges = (const int*)d_in[2];
    const int F = in_sizes[3];           // 69
    const int NP = in_sizes[0] / F;
    const int NC = in_sizes[1] / F;
    const int E = in_sizes[2] / 2;
    const int* src = edges;
    const int* dst = edges + E;

    const float *pe_shift = (const float*)d_in[3], *pe_scale = (const float*)d_in[4],
                *pe_w1 = (const float*)d_in[5], *pe_b1 = (const float*)d_in[6],
                *pe_w2 = (const float*)d_in[7], *pe_b2 = (const float*)d_in[8];
    const float *ce_shift = (const float*)d_in[9], *ce_scale = (const float*)d_in[10],
                *ce_w1 = (const float*)d_in[11], *ce_b1 = (const float*)d_in[12],
                *ce_w2 = (const float*)d_in[13], *ce_b2 = (const float*)d_in[14];
    const float *vc_wl = (const float*)d_in[15], *vc_bl = (const float*)d_in[16],
                *vc_wr = (const float*)d_in[17], *vc_sf = (const float*)d_in[18],
                *vc_wf = (const float*)d_in[19], *vc_bf = (const float*)d_in[20],
                *vc_sp = (const float*)d_in[21], *vc_wo1 = (const float*)d_in[22],
                *vc_bo1 = (const float*)d_in[23], *vc_wo2 = (const float*)d_in[24],
                *vc_bo2 = (const float*)d_in[25];
    const float *cv_wl = (const float*)d_in[26], *cv_bl = (const float*)d_in[27],
                *cv_wr = (const float*)d_in[28], *cv_sf = (const float*)d_in[29],
                *cv_wf = (const float*)d_in[30], *cv_bf = (const float*)d_in[31],
                *cv_sp = (const float*)d_in[32], *cv_wo1 = (const float*)d_in[33],
                *cv_bo1 = (const float*)d_in[34], *cv_wo2 = (const float*)d_in[35],
                *cv_bo2 = (const float*)d_in[36];
    const float *out_w1 = (const float*)d_in[37], *out_b1 = (const float*)d_in[38],
                *out_w2 = (const float*)d_in[39], *out_b2 = (const float*)d_in[40];

    const size_t NP128 = (size_t)NP * 128, NC128 = (size_t)NC * 128;
    const int NMAX = (NC > NP) ? NC : NP;
    float* ws = (float*)d_ws;
    float* W0 = ws;               // [NP,128] pv0
    float* W1 = W0 + NP128;       // [NC,128] ch0 -> Sdiv_p -> pv1
    float* W2 = W1 + NC128;       // [NC,128] scratch
    float* W3 = W2 + NC128;       // [NC,128] scratch
    float* W4 = W3 + NC128;       // [NC,128] Sdiv_c -> ch1
    float* W5 = W4 + NC128;       // [NMAX]   cntf
    int* ip = (int*)(W5 + NMAX);
    int* cnt_c = ip;              // [NC]
    int* off_c = cnt_c + NC;      // [NC]
    int* cnt_p = off_c + NC;      // [NP]
    int* off_p = cnt_p + NP;      // [NP]
    int* fill = off_p + NP;       // [NMAX]
    int* adj_c = fill + NMAX;     // [E] src sorted by dst
    int* adj_p = adj_c + E;       // [E] dst sorted by src
    int* totals = adj_p + E;      // [2]

    auto gemm = [&](const float* A1, const float* A2, const float* Wp, const float* b,
                    const float* sh, const float* sc, const float* gt,
                    const float* a1s, float* o, int M, int K, int Ksplit, int relu) {
        hipLaunchKernelGGL(gemm_fused, dim3((M + 63) / 64), dim3(256), 0, stream,
                           A1, A2, Wp, b, sh, sc, gt, a1s, o, M, K, Ksplit, relu);
    };
    const int EB = (E + 255) / 256;

    // --- CSR build (both directions) ---
    hipMemsetAsync(cnt_c, 0, (size_t)NC * sizeof(int), stream);
    hipMemsetAsync(cnt_p, 0, (size_t)NP * sizeof(int), stream);
    hipMemsetAsync(totals, 0, 2 * sizeof(int), stream);
    hipLaunchKernelGGL(hist_kernel, dim3(EB), dim3(256), 0, stream, dst, cnt_c, E);
    hipLaunchKernelGGL(hist_kernel, dim3(EB), dim3(256), 0, stream, src, cnt_p, E);
    hipLaunchKernelGGL(offsets_kernel, dim3((NC + 255) / 256), dim3(256), 0, stream,
                       cnt_c, off_c, totals + 0, NC);
    hipLaunchKernelGGL(offsets_kernel, dim3((NP + 255) / 256), dim3(256), 0, stream,
                       cnt_p, off_p, totals + 1, NP);
    hipMemsetAsync(fill, 0, (size_t)NC * sizeof(int), stream);
    hipLaunchKernelGGL(scatter_adj, dim3(EB), dim3(256), 0, stream,
                       dst, src, off_c, fill, adj_c, E);
    hipMemsetAsync(fill, 0, (size_t)NP * sizeof(int), stream);
    hipLaunchKernelGGL(scatter_adj, dim3(EB), dim3(256), 0, stream,
                       src, dst, off_p, fill, adj_p, E);

    // --- embeddings ---
    gemm(pivot, nullptr, pe_w1, pe_b1, pe_shift, pe_scale, nullptr, nullptr,
         W2, NP, F, F, 1);
    gemm(W2, nullptr, pe_w2, pe_b2, nullptr, nullptr, nullptr, nullptr,
         W0, NP, 128, 128, 1);                                   // pv0
    gemm(child, nullptr, ce_w1, ce_b1, ce_shift, ce_scale, nullptr, nullptr,
         W2, NC, F, F, 1);
    gemm(W2, nullptr, ce_w2, ce_b2, nullptr, nullptr, nullptr, nullptr,
         W1, NC, 128, 128, 1);                                   // ch0

    // --- conv v->c (aggregate to children) ---
    gemm(W1, nullptr, vc_wl, vc_bl, nullptr, nullptr, nullptr, nullptr,
         W2, NC, 128, 128, 0);                                   // RW = ch0@wl+bl
    gemm(W0, nullptr, vc_wr, nullptr, nullptr, nullptr, nullptr, nullptr,
         W3, NP, 128, 128, 0);                                   // LW = pv0@wr
    hipLaunchKernelGGL(node_gather, dim3(((size_t)NC * 32 + 255) / 256), dim3(256), 0,
                       stream, off_c, cnt_c, adj_c, W2, W3, W4, W5, vc_sf, NC);
    gemm(W4, nullptr, vc_wf, vc_bf, nullptr, nullptr, W5, nullptr,
         W3, NC, 128, 128, 0);                                   // agg_c
    gemm(W3, W1, vc_wo1, vc_bo1, nullptr, nullptr, nullptr, vc_sp,
         W2, NC, 256, 128, 1);
    gemm(W2, nullptr, vc_wo2, vc_bo2, nullptr, nullptr, nullptr, nullptr,
         W4, NC, 128, 128, 0);                                   // ch1

    // --- conv c->v (aggregate to pivot) ---
    gemm(W0, nullptr, cv_wl, cv_bl, nullptr, nullptr, nullptr, nullptr,
         W2, NP, 128, 128, 0);                                   // RW_p = pv0@wl+bl
    gemm(W4, nullptr, cv_wr, nullptr, nullptr, nullptr, nullptr, nullptr,
         W3, NC, 128, 128, 0);                                   // LW_c = ch1@wr
    hipLaunchKernelGGL(node_gather, dim3(((size_t)NP * 32 + 255) / 256), dim3(256), 0,
                       stream, off_p, cnt_p, adj_p, W2, W3, W1, W5, cv_sf, NP);
    gemm(W1, nullptr, cv_wf, cv_bf, nullptr, nullptr, W5, nullptr,
         W2, NP, 128, 128, 0);                                   // agg_p
    gemm(W2, W0, cv_wo1, cv_bo1, nullptr, nullptr, nullptr, cv_sp,
         W3, NP, 256, 128, 1);
    gemm(W3, nullptr, cv_wo2, cv_bo2, nullptr, nullptr, nullptr, nullptr,
         W1, NP, 128, 128, 0);                                   // pv1

    // --- head ---
    gemm(W1, nullptr, out_w1, out_b1, nullptr, nullptr, nullptr, nullptr,
         W2, NP, 128, 128, 1);
    hipLaunchKernelGGL(final_head, dim3((NP + 3) / 4), dim3(256), 0, stream,
                       W2, out_w2, out_b2, (float*)d_out, NP);
}

// Round 3
// 726.272 us; speedup vs baseline: 4.5992x; 2.0021x over previous
//
#include <hip/hip_runtime.h>
#include <math.h>

// ---------------------------------------------------------------------------
// Round 3: bf16 activations + MFMA GEMMs.
//   - wconvert: all weights -> bf16 W^T[col][k], padded (69->96), sp folded.
//   - featconv: fp32 features + prenorm -> bf16 [M,96].
//   - mfma_gemm: 1 wave / 16-row tile, A-frags direct from global,
//     B-frags re-read from L2-hot W^T, fp32 accum, fused bias/gate/relu.
//   - CSR build + bf16 gather unchanged in structure from round 2.
// ---------------------------------------------------------------------------

typedef unsigned short u16;
typedef __attribute__((ext_vector_type(8))) short s8v;   // 8 bf16 = 4 VGPR
typedef __attribute__((ext_vector_type(4))) float f4v;   // MFMA C/D frag

__device__ __forceinline__ float bf2f(u16 u) {
    unsigned x = ((unsigned)u) << 16;
    return __builtin_bit_cast(float, x);
}
__device__ __forceinline__ u16 f2bf(float f) {
    unsigned x = __builtin_bit_cast(unsigned, f);
    unsigned r = x + 0x7fffu + ((x >> 16) & 1u);
    return (u16)(r >> 16);
}

// ---- weight conversion: fp32 [Ksrc][128] -> bf16 WT[col*Kdst + k], pad k ----
struct WEnt { const float* src; const float* sp; int Ksrc; int Kdst; };
struct WPack { WEnt e[15]; };

__global__ __launch_bounds__(256) void wconvert(WPack p, u16* __restrict__ wt)
{
    int t = blockIdx.x * 256 + threadIdx.x;
    int m = t >> 15;            // 32768 slot per matrix
    int i = t & 32767;
    WEnt en = p.e[m];
    if (i >= (en.Kdst << 7)) return;
    int k = i >> 7, col = i & 127;
    float v = 0.f;
    if (k < en.Ksrc) {
        v = en.src[k * 128 + col];
        if (en.sp && k < 128) v *= *en.sp;
    }
    wt[(size_t)m * 32768 + (size_t)col * en.Kdst + k] = f2bf(v);
}

// ---- feature conversion: fp32 [M,F] -> bf16 [M,96] with prenorm ----
__global__ __launch_bounds__(256) void featconv(
    const float* __restrict__ x, const float* __restrict__ shift,
    const float* __restrict__ scale, u16* __restrict__ y,
    long total, int F)
{
    for (long i = (long)blockIdx.x * 256 + threadIdx.x; i < total;
         i += (long)gridDim.x * 256) {
        int c = (int)(i % 96);
        long r = i / 96;
        float v = 0.f;
        if (c < F) {
            v = x[r * F + c];
            v = (v + shift[c]) * scale[c];
        }
        y[i] = f2bf(v);
    }
}

// ---- MFMA GEMM: out[M,128] = act( [A1(,A2)] @ W + bias*gate ) ----
template <int K1, bool HASA2, bool RELU, bool GATE>
__global__ __launch_bounds__(256) void mfma_gemm(
    const u16* __restrict__ A1, const u16* __restrict__ A2,
    const u16* __restrict__ WT,        // bf16 [128][KT]
    const float* __restrict__ bias,    // fp32 [128] or null
    const float* __restrict__ gate,    // fp32 [M] (cnt) when GATE
    u16* __restrict__ out, int M)
{
    constexpr int KT = K1 + (HASA2 ? 128 : 0);
    const int lane = threadIdx.x & 63;
    const int wv = threadIdx.x >> 6;
    const int col = lane & 15;      // A row-in-tile / B col-in-tile
    const int kg = lane >> 4;       // k-group 0..3
    const int koff = kg * 8;
    const int ntile = M >> 4;

    for (int tile = blockIdx.x * 4 + wv; tile < ntile; tile += gridDim.x * 4) {
        const int r0 = tile * 16;
        f4v acc[8];
#pragma unroll
        for (int nt = 0; nt < 8; ++nt) acc[nt] = (f4v){0.f, 0.f, 0.f, 0.f};

        const u16* a1p = A1 + (size_t)(r0 + col) * K1 + koff;
        const u16* wtp = WT + (size_t)col * KT + koff;
#pragma unroll
        for (int ks = 0; ks < K1 / 32; ++ks) {
            s8v a = *(const s8v*)(a1p + ks * 32);
#pragma unroll
            for (int nt = 0; nt < 8; ++nt) {
                s8v b = *(const s8v*)(wtp + (size_t)nt * 16 * KT + ks * 32);
                acc[nt] = __builtin_amdgcn_mfma_f32_16x16x32_bf16(a, b, acc[nt], 0, 0, 0);
            }
        }
        if (HASA2) {
            const u16* a2p = A2 + (size_t)(r0 + col) * 128 + koff;
#pragma unroll
            for (int ks = 0; ks < 4; ++ks) {
                s8v a = *(const s8v*)(a2p + ks * 32);
#pragma unroll
                for (int nt = 0; nt < 8; ++nt) {
                    s8v b = *(const s8v*)(wtp + (size_t)nt * 16 * KT + K1 + ks * 32);
                    acc[nt] = __builtin_amdgcn_mfma_f32_16x16x32_bf16(a, b, acc[nt], 0, 0, 0);
                }
            }
        }
        // epilogue: C/D frag j -> row r0+kg*4+j, col nt*16+col
        float bc[8];
#pragma unroll
        for (int nt = 0; nt < 8; ++nt) bc[nt] = bias ? bias[nt * 16 + col] : 0.f;
        float g4[4];
#pragma unroll
        for (int j = 0; j < 4; ++j)
            g4[j] = GATE ? (gate[r0 + kg * 4 + j] > 0.f ? 1.f : 0.f) : 1.f;
#pragma unroll
        for (int nt = 0; nt < 8; ++nt) {
            int c = nt * 16 + col;
#pragma unroll
            for (int j = 0; j < 4; ++j) {
                int rr = r0 + kg * 4 + j;
                float v = acc[nt][j] + bc[nt] * g4[j];
                if (RELU) v = fmaxf(v, 0.f);
                out[(size_t)rr * 128 + c] = f2bf(v);
            }
        }
    }
}

// ---- CSR build ----
__global__ __launch_bounds__(256) void hist_kernel(
    const int* __restrict__ key, int* __restrict__ cnt, int E)
{
    int e = blockIdx.x * 256 + threadIdx.x;
    if (e < E) atomicAdd(&cnt[key[e]], 1);
}

__global__ __launch_bounds__(256) void offsets_kernel(
    const int* __restrict__ cnt, int* __restrict__ off,
    int* __restrict__ total, int N)
{
    int n = blockIdx.x * 256 + threadIdx.x;
    int lane = threadIdx.x & 63;
    int v = (n < N) ? cnt[n] : 0;
    int incl = v;
#pragma unroll
    for (int d = 1; d < 64; d <<= 1) {
        int up = __shfl_up(incl, d);
        if (lane >= d) incl += up;
    }
    int wave_sum = __shfl(incl, 63);
    int base = 0;
    if (lane == 63) base = atomicAdd(total, wave_sum);
    base = __shfl(base, 63);
    if (n < N) off[n] = base + incl - v;
}

__global__ __launch_bounds__(256) void scatter_adj(
    const int* __restrict__ key, const int* __restrict__ val,
    const int* __restrict__ off, int* __restrict__ fill,
    int* __restrict__ adj, int E)
{
    int e = blockIdx.x * 256 + threadIdx.x;
    if (e < E) {
        int k = key[e];
        int p = off[k] + atomicAdd(&fill[k], 1);
        adj[p] = val[e];
    }
}

// ---- gather aggregation (bf16): Sdiv[n] = mean_e relu((RW[n]+LW[adj])*sf) ----
__global__ __launch_bounds__(256) void node_gather(
    const int* __restrict__ off, const int* __restrict__ cnt,
    const int* __restrict__ adj,
    const u16* __restrict__ RW, const u16* __restrict__ LW,
    u16* __restrict__ Sdiv, float* __restrict__ cntf,
    const float* __restrict__ sf_p, int N)
{
    int t = blockIdx.x * 256 + threadIdx.x;
    int n = t >> 5;
    if (n >= N) return;
    int lane = t & 31;
    const float sf = *sf_p;
    int start = off[n], len = cnt[n];
    uint2 ru = *(const uint2*)(RW + (size_t)n * 128 + lane * 4);
    float r0 = bf2f((u16)(ru.x & 0xffff)), r1 = bf2f((u16)(ru.x >> 16));
    float r2 = bf2f((u16)(ru.y & 0xffff)), r3 = bf2f((u16)(ru.y >> 16));
    float a0 = 0.f, a1 = 0.f, a2 = 0.f, a3 = 0.f;
    for (int i = 0; i < len; ++i) {
        int l = adj[start + i];
        uint2 lu = *(const uint2*)(LW + (size_t)l * 128 + lane * 4);
        a0 += fmaxf((r0 + bf2f((u16)(lu.x & 0xffff))) * sf, 0.f);
        a1 += fmaxf((r1 + bf2f((u16)(lu.x >> 16))) * sf, 0.f);
        a2 += fmaxf((r2 + bf2f((u16)(lu.y & 0xffff))) * sf, 0.f);
        a3 += fmaxf((r3 + bf2f((u16)(lu.y >> 16))) * sf, 0.f);
    }
    float inv = 1.f / fmaxf((float)len, 1.f);
    uint2 o;
    o.x = (unsigned)f2bf(a0 * inv) | ((unsigned)f2bf(a1 * inv) << 16);
    o.y = (unsigned)f2bf(a2 * inv) | ((unsigned)f2bf(a3 * inv) << 16);
    *(uint2*)(Sdiv + (size_t)n * 128 + lane * 4) = o;
    if (lane == 0) cntf[n] = (float)len;
}

// ---- head: out[row,0..1] = sigmoid(T[row] @ w2 + b2) ----
__global__ __launch_bounds__(256) void final_head(
    const u16* __restrict__ T, const float* __restrict__ w2,
    const float* __restrict__ b2, float* __restrict__ out, int M)
{
    int wid = threadIdx.x >> 6, lane = threadIdx.x & 63;
    int row = blockIdx.x * 4 + wid;
    if (row >= M) return;
    unsigned u = *(const unsigned*)(T + (size_t)row * 128 + lane * 2);
    float x0 = bf2f((u16)(u & 0xffff)), x1 = bf2f((u16)(u >> 16));
    int k0 = lane * 2, k1 = lane * 2 + 1;
    float p0 = x0 * w2[k0 * 2 + 0] + x1 * w2[k1 * 2 + 0];
    float p1 = x0 * w2[k0 * 2 + 1] + x1 * w2[k1 * 2 + 1];
#pragma unroll
    for (int o = 32; o > 0; o >>= 1) {
        p0 += __shfl_xor(p0, o);
        p1 += __shfl_xor(p1, o);
    }
    if (lane == 0) {
        out[(size_t)row * 2 + 0] = 1.f / (1.f + expf(-(p0 + b2[0])));
        out[(size_t)row * 2 + 1] = 1.f / (1.f + expf(-(p1 + b2[1])));
    }
}

extern "C" void kernel_launch(void* const* d_in, const int* in_sizes, int n_in,
                              void* d_out, int out_size, void* d_ws, size_t ws_size,
                              hipStream_t stream)
{
    const float* pivot = (const float*)d_in[0];
    const float* child = (const float*)d_in[1];
    const int* edges = (const int*)d_in[2];
    const int F = in_sizes[3];           // 69
    const int NP = in_sizes[0] / F;
    const int NC = in_sizes[1] / F;
    const int E = in_sizes[2] / 2;
    const int* src = edges;
    const int* dst = edges + E;

    const float *pe_shift = (const float*)d_in[3], *pe_scale = (const float*)d_in[4],
                *pe_w1 = (const float*)d_in[5], *pe_b1 = (const float*)d_in[6],
                *pe_w2 = (const float*)d_in[7], *pe_b2 = (const float*)d_in[8];
    const float *ce_shift = (const float*)d_in[9], *ce_scale = (const float*)d_in[10],
                *ce_w1 = (const float*)d_in[11], *ce_b1 = (const float*)d_in[12],
                *ce_w2 = (const float*)d_in[13], *ce_b2 = (const float*)d_in[14];
    const float *vc_wl = (const float*)d_in[15], *vc_bl = (const float*)d_in[16],
                *vc_wr = (const float*)d_in[17], *vc_sf = (const float*)d_in[18],
                *vc_wf = (const float*)d_in[19], *vc_bf = (const float*)d_in[20],
                *vc_sp = (const float*)d_in[21], *vc_wo1 = (const float*)d_in[22],
                *vc_bo1 = (const float*)d_in[23], *vc_wo2 = (const float*)d_in[24],
                *vc_bo2 = (const float*)d_in[25];
    const float *cv_wl = (const float*)d_in[26], *cv_bl = (const float*)d_in[27],
                *cv_wr = (const float*)d_in[28], *cv_sf = (const float*)d_in[29],
                *cv_wf = (const float*)d_in[30], *cv_bf = (const float*)d_in[31],
                *cv_sp = (const float*)d_in[32], *cv_wo1 = (const float*)d_in[33],
                *cv_bo1 = (const float*)d_in[34], *cv_wo2 = (const float*)d_in[35],
                *cv_bo2 = (const float*)d_in[36];
    const float *out_w1 = (const float*)d_in[37], *out_b1 = (const float*)d_in[38],
                *out_w2 = (const float*)d_in[39], *out_b2 = (const float*)d_in[40];

    // ---- workspace carve (256B aligned) ----
    char* base = (char*)d_ws;
    size_t off = 0;
    auto carve = [&](size_t bytes) {
        void* p = base + off;
        off += (bytes + 255) & ~(size_t)255;
        return p;
    };
    u16* WT = (u16*)carve((size_t)15 * 32768 * 2);
    u16* FP = (u16*)carve((size_t)NP * 96 * 2);
    u16* FC = (u16*)carve((size_t)NC * 96 * 2);
    u16* B0 = (u16*)carve((size_t)NP * 128 * 2);   // pv0
    u16* B1 = (u16*)carve((size_t)NC * 128 * 2);
    u16* B2 = (u16*)carve((size_t)NC * 128 * 2);
    u16* B3 = (u16*)carve((size_t)NC * 128 * 2);
    u16* B4 = (u16*)carve((size_t)NC * 128 * 2);
    const int NMAX = (NC > NP) ? NC : NP;
    float* cntf = (float*)carve((size_t)NMAX * 4);
    int* cnt_c = (int*)carve((size_t)(2 * NC + 2 * NP + 2) * 4);  // one memset
    int* cnt_p = cnt_c + NC;
    int* fill_c = cnt_p + NP;
    int* fill_p = fill_c + NC;
    int* totals = fill_p + NP;
    int* off_c = (int*)carve((size_t)NC * 4);
    int* off_p = (int*)carve((size_t)NP * 4);
    int* adj_c = (int*)carve((size_t)E * 4);
    int* adj_p = (int*)carve((size_t)E * 4);

    // ---- weight conversion ----
    WPack wp;
    auto setw = [&](int i, const float* s, int ks, int kd, const float* sp) {
        wp.e[i].src = s; wp.e[i].sp = sp; wp.e[i].Ksrc = ks; wp.e[i].Kdst = kd;
    };
    setw(0, pe_w1, F, 96, nullptr);   setw(1, pe_w2, 128, 128, nullptr);
    setw(2, ce_w1, F, 96, nullptr);   setw(3, ce_w2, 128, 128, nullptr);
    setw(4, vc_wl, 128, 128, nullptr); setw(5, vc_wr, 128, 128, nullptr);
    setw(6, vc_wf, 128, 128, nullptr); setw(7, vc_wo1, 256, 256, vc_sp);
    setw(8, vc_wo2, 128, 128, nullptr);
    setw(9, cv_wl, 128, 128, nullptr); setw(10, cv_wr, 128, 128, nullptr);
    setw(11, cv_wf, 128, 128, nullptr); setw(12, cv_wo1, 256, 256, cv_sp);
    setw(13, cv_wo2, 128, 128, nullptr); setw(14, out_w1, 128, 128, nullptr);
    hipLaunchKernelGGL(wconvert, dim3(15 * 128), dim3(256), 0, stream, wp, WT);
    auto wt = [&](int i) { return WT + (size_t)i * 32768; };

    // ---- feature conversion ----
    hipLaunchKernelGGL(featconv, dim3(2048), dim3(256), 0, stream,
                       pivot, pe_shift, pe_scale, FP, (long)NP * 96, F);
    hipLaunchKernelGGL(featconv, dim3(2048), dim3(256), 0, stream,
                       child, ce_shift, ce_scale, FC, (long)NC * 96, F);

    // ---- CSR build ----
    const int EB = (E + 255) / 256;
    hipMemsetAsync(cnt_c, 0, (size_t)(2 * NC + 2 * NP + 2) * 4, stream);
    hipLaunchKernelGGL(hist_kernel, dim3(EB), dim3(256), 0, stream, dst, cnt_c, E);
    hipLaunchKernelGGL(hist_kernel, dim3(EB), dim3(256), 0, stream, src, cnt_p, E);
    hipLaunchKernelGGL(offsets_kernel, dim3((NC + 255) / 256), dim3(256), 0, stream,
                       cnt_c, off_c, totals + 0, NC);
    hipLaunchKernelGGL(offsets_kernel, dim3((NP + 255) / 256), dim3(256), 0, stream,
                       cnt_p, off_p, totals + 1, NP);
    hipLaunchKernelGGL(scatter_adj, dim3(EB), dim3(256), 0, stream,
                       dst, src, off_c, fill_c, adj_c, E);
    hipLaunchKernelGGL(scatter_adj, dim3(EB), dim3(256), 0, stream,
                       src, dst, off_p, fill_p, adj_p, E);

    // ---- GEMM helpers ----
    auto grd = [](int M) { return dim3(((M >> 4) + 3) / 4); };
    const dim3 blk(256);

    // embeddings
    mfma_gemm<96, false, true, false><<<grd(NP), blk, 0, stream>>>(
        FP, nullptr, wt(0), pe_b1, nullptr, B1, NP);
    mfma_gemm<128, false, true, false><<<grd(NP), blk, 0, stream>>>(
        B1, nullptr, wt(1), pe_b2, nullptr, B0, NP);            // pv0
    mfma_gemm<96, false, true, false><<<grd(NC), blk, 0, stream>>>(
        FC, nullptr, wt(2), ce_b1, nullptr, B1, NC);
    mfma_gemm<128, false, true, false><<<grd(NC), blk, 0, stream>>>(
        B1, nullptr, wt(3), ce_b2, nullptr, B2, NC);            // ch0

    // conv v->c (aggregate to children)
    mfma_gemm<128, false, false, false><<<grd(NC), blk, 0, stream>>>(
        B2, nullptr, wt(4), vc_bl, nullptr, B1, NC);            // RW = ch0@wl+bl
    mfma_gemm<128, false, false, false><<<grd(NP), blk, 0, stream>>>(
        B0, nullptr, wt(5), nullptr, nullptr, B3, NP);          // LW = pv0@wr
    hipLaunchKernelGGL(node_gather, dim3(((size_t)NC * 32 + 255) / 256), blk, 0,
                       stream, off_c, cnt_c, adj_c, B1, B3, B4, cntf, vc_sf, NC);
    mfma_gemm<128, false, false, true><<<grd(NC), blk, 0, stream>>>(
        B4, nullptr, wt(6), vc_bf, cntf, B1, NC);               // agg
    mfma_gemm<128, true, true, false><<<grd(NC), blk, 0, stream>>>(
        B1, B2, wt(7), vc_bo1, nullptr, B3, NC);                // relu([agg*sp,ch0]@wo1+bo1)
    mfma_gemm<128, false, false, false><<<grd(NC), blk, 0, stream>>>(
        B3, nullptr, wt(8), vc_bo2, nullptr, B4, NC);           // ch1

    // conv c->v (aggregate to pivot)
    mfma_gemm<128, false, false, false><<<grd(NP), blk, 0, stream>>>(
        B0, nullptr, wt(9), cv_bl, nullptr, B1, NP);            // RW_p = pv0@wl+bl
    mfma_gemm<128, false, false, false><<<grd(NC), blk, 0, stream>>>(
        B4, nullptr, wt(10), nullptr, nullptr, B3, NC);         // LW_c = ch1@wr
    hipLaunchKernelGGL(node_gather, dim3(((size_t)NP * 32 + 255) / 256), blk, 0,
                       stream, off_p, cnt_p, adj_p, B1, B3, B2, cntf, cv_sf, NP);
    mfma_gemm<128, false, false, true><<<grd(NP), blk, 0, stream>>>(
        B2, nullptr, wt(11), cv_bf, cntf, B1, NP);              // agg_p
    mfma_gemm<128, true, true, false><<<grd(NP), blk, 0, stream>>>(
        B1, B0, wt(12), cv_bo1, nullptr, B2, NP);
    mfma_gemm<128, false, false, false><<<grd(NP), blk, 0, stream>>>(
        B2, nullptr, wt(13), cv_bo2, nullptr, B1, NP);          // pv1

    // head
    mfma_gemm<128, false, true, false><<<grd(NP), blk, 0, stream>>>(
        B1, nullptr, wt(14), out_b1, nullptr, B2, NP);
    hipLaunchKernelGGL(final_head, dim3((NP + 3) / 4), blk, 0, stream,
                       B2, out_w2, out_b2, (float*)d_out, NP);
}

// Round 4
// 518.233 us; speedup vs baseline: 6.4455x; 1.4014x over previous
//
#include <hip/hip_runtime.h>
#include <math.h>

// ---------------------------------------------------------------------------
// Round 4: register-persistent-B MFMA GEMMs + A-prefetch + fused head.
//   - Each wave loads W^T fragments ONCE into VGPRs (128 regs for K=128),
//     then streams 16-row A-tiles: 4 coalesced loads (1-ahead prefetch)
//     + 32 MFMA + store. No per-tile B loads (round 3's latency bottleneck).
//   - K=256 concat GEMM: persist ks0..3, stream ks4..7 from L2-hot W^T.
//   - Head fused: last GEMM C-frags dotted with out_w2 in-register
//     (shfl_xor over 16-lane col group), sigmoid, write [NP,2] fp32.
//   - CSR build + gather unchanged from round 3.
// ---------------------------------------------------------------------------

typedef unsigned short u16;
typedef __attribute__((ext_vector_type(8))) short s8v;   // 8 bf16 = 4 VGPR
typedef __attribute__((ext_vector_type(4))) float f4v;   // MFMA C/D frag

__device__ __forceinline__ float bf2f(u16 u) {
    unsigned x = ((unsigned)u) << 16;
    return __builtin_bit_cast(float, x);
}
__device__ __forceinline__ u16 f2bf(float f) {
    unsigned x = __builtin_bit_cast(unsigned, f);
    unsigned r = x + 0x7fffu + ((x >> 16) & 1u);
    return (u16)(r >> 16);
}

// ---- weight conversion: fp32 [Ksrc][128] -> bf16 WT[col*Kdst + k], pad k ----
struct WEnt { const float* src; const float* sp; int Ksrc; int Kdst; };
struct WPack { WEnt e[15]; };

__global__ __launch_bounds__(256) void wconvert(WPack p, u16* __restrict__ wt)
{
    int t = blockIdx.x * 256 + threadIdx.x;
    int m = t >> 15;            // 32768 slots per matrix
    int i = t & 32767;
    WEnt en = p.e[m];
    if (i >= (en.Kdst << 7)) return;
    int k = i >> 7, col = i & 127;
    float v = 0.f;
    if (k < en.Ksrc) {
        v = en.src[k * 128 + col];
        if (en.sp && k < 128) v *= *en.sp;
    }
    wt[(size_t)m * 32768 + (size_t)col * en.Kdst + k] = f2bf(v);
}

// ---- feature conversion: fp32 [M,F] -> bf16 [M,96] with prenorm ----
__global__ __launch_bounds__(256) void featconv(
    const float* __restrict__ x, const float* __restrict__ shift,
    const float* __restrict__ scale, u16* __restrict__ y,
    long total, int F)
{
    for (long i = (long)blockIdx.x * 256 + threadIdx.x; i < total;
         i += (long)gridDim.x * 256) {
        int c = (int)(i % 96);
        long r = i / 96;
        float v = 0.f;
        if (c < F) {
            v = x[r * F + c];
            v = (v + shift[c]) * scale[c];
        }
        y[i] = f2bf(v);
    }
}

// ---- register-persistent-B GEMM: out[M,128] = act([A1|A2] @ W + bias*g) ----
template <int KS, bool HASA2, bool RELU, bool GATE>
__global__ __launch_bounds__(256) void gemm_rb(
    const u16* __restrict__ A1, const u16* __restrict__ A2,
    const u16* __restrict__ WT,      // bf16 [128][KS*32] col-major
    const float* __restrict__ bias,  // fp32 [128] or null
    const float* __restrict__ gate,  // fp32 [M] (cnt) when GATE
    u16* __restrict__ out, int M)    // M % 16 == 0
{
    constexpr int KT = KS * 32;
    constexpr int K1 = HASA2 ? 128 : KT;
    constexpr int KP = (KS > 4) ? 4 : KS;   // persisted ks blocks
    constexpr bool PF = (KS <= 4);          // A prefetch (reg budget)
    const int lane = threadIdx.x & 63;
    const int c = lane & 15;
    const int kg = lane >> 4;
    const int wid = blockIdx.x * 4 + (threadIdx.x >> 6);
    const int wstride = gridDim.x * 4;
    const int items = M >> 4;

    // persist B fragments: bp[ks][nt] covers cols nt*16+c, k ks*32+kg*8..+7
    const u16* wbase = WT + (size_t)c * KT + kg * 8;
    s8v bp[KP][8];
#pragma unroll
    for (int ks = 0; ks < KP; ++ks)
#pragma unroll
        for (int nt = 0; nt < 8; ++nt)
            bp[ks][nt] = *(const s8v*)(wbase + ((size_t)nt * 16) * KT + ks * 32);

    float bc[8];
#pragma unroll
    for (int nt = 0; nt < 8; ++nt) bc[nt] = bias ? bias[nt * 16 + c] : 0.f;

    auto lda = [&](s8v* a, int item) {
        const u16* ap = A1 + (size_t)((item << 4) + c) * K1 + kg * 8;
#pragma unroll
        for (int ks = 0; ks < (HASA2 ? 4 : KS); ++ks)
            a[ks] = *(const s8v*)(ap + ks * 32);
        if (HASA2) {
            const u16* ap2 = A2 + (size_t)((item << 4) + c) * 128 + kg * 8;
#pragma unroll
            for (int ks = 0; ks < 4; ++ks) a[4 + ks] = *(const s8v*)(ap2 + ks * 32);
        }
    };

    s8v a[KS], an[KS];
    int item = wid;
    if (item < items) lda(a, item);
    while (item < items) {
        const int nitem = item + wstride;
        if (PF && nitem < items) lda(an, nitem);

        f4v acc[8];
#pragma unroll
        for (int nt = 0; nt < 8; ++nt) acc[nt] = (f4v){0.f, 0.f, 0.f, 0.f};
#pragma unroll
        for (int ks = 0; ks < KP; ++ks)
#pragma unroll
            for (int nt = 0; nt < 8; ++nt)
                acc[nt] = __builtin_amdgcn_mfma_f32_16x16x32_bf16(a[ks], bp[ks][nt], acc[nt], 0, 0, 0);
        if (KS > KP) {
#pragma unroll
            for (int ks = KP; ks < KS; ++ks)
#pragma unroll
                for (int nt = 0; nt < 8; ++nt) {
                    s8v b = *(const s8v*)(wbase + ((size_t)nt * 16) * KT + ks * 32);
                    acc[nt] = __builtin_amdgcn_mfma_f32_16x16x32_bf16(a[ks], b, acc[nt], 0, 0, 0);
                }
        }

        const int r0 = item << 4;
        float g4[4];
#pragma unroll
        for (int j = 0; j < 4; ++j)
            g4[j] = GATE ? (gate[r0 + kg * 4 + j] > 0.f ? 1.f : 0.f) : 1.f;
#pragma unroll
        for (int nt = 0; nt < 8; ++nt)
#pragma unroll
            for (int j = 0; j < 4; ++j) {
                float v = acc[nt][j] + bc[nt] * g4[j];
                if (RELU) v = fmaxf(v, 0.f);
                out[(size_t)(r0 + kg * 4 + j) * 128 + nt * 16 + c] = f2bf(v);
            }

        if (PF) {
            if (nitem < items) {
#pragma unroll
                for (int ks = 0; ks < KS; ++ks) a[ks] = an[ks];
            }
        } else if (nitem < items) {
            lda(a, nitem);
        }
        item = nitem;
    }
}

// ---- fused head: sigmoid(relu(A@W1+b1) @ w2 + b2) -> [M,2] fp32 ----
__global__ __launch_bounds__(256) void head_fused(
    const u16* __restrict__ A1, const u16* __restrict__ WT,
    const float* __restrict__ b1, const float* __restrict__ w2,
    const float* __restrict__ b2, float* __restrict__ outp, int M)
{
    constexpr int KT = 128;
    const int lane = threadIdx.x & 63;
    const int c = lane & 15;
    const int kg = lane >> 4;
    const int wid = blockIdx.x * 4 + (threadIdx.x >> 6);
    const int wstride = gridDim.x * 4;
    const int items = M >> 4;

    const u16* wbase = WT + (size_t)c * KT + kg * 8;
    s8v bp[4][8];
#pragma unroll
    for (int ks = 0; ks < 4; ++ks)
#pragma unroll
        for (int nt = 0; nt < 8; ++nt)
            bp[ks][nt] = *(const s8v*)(wbase + ((size_t)nt * 16) * KT + ks * 32);

    float bc[8], w2c0[8], w2c1[8];
#pragma unroll
    for (int nt = 0; nt < 8; ++nt) {
        int col = nt * 16 + c;
        bc[nt] = b1[col];
        w2c0[nt] = w2[col * 2 + 0];
        w2c1[nt] = w2[col * 2 + 1];
    }
    const float s0 = b2[0], s1 = b2[1];

    for (int item = wid; item < items; item += wstride) {
        const int r0 = item << 4;
        const u16* ap = A1 + (size_t)(r0 + c) * 128 + kg * 8;
        s8v a[4];
#pragma unroll
        for (int ks = 0; ks < 4; ++ks) a[ks] = *(const s8v*)(ap + ks * 32);

        f4v acc[8];
#pragma unroll
        for (int nt = 0; nt < 8; ++nt) acc[nt] = (f4v){0.f, 0.f, 0.f, 0.f};
#pragma unroll
        for (int ks = 0; ks < 4; ++ks)
#pragma unroll
            for (int nt = 0; nt < 8; ++nt)
                acc[nt] = __builtin_amdgcn_mfma_f32_16x16x32_bf16(a[ks], bp[ks][nt], acc[nt], 0, 0, 0);

        float pp0[4] = {0.f, 0.f, 0.f, 0.f}, pp1[4] = {0.f, 0.f, 0.f, 0.f};
#pragma unroll
        for (int nt = 0; nt < 8; ++nt)
#pragma unroll
            for (int j = 0; j < 4; ++j) {
                float v = fmaxf(acc[nt][j] + bc[nt], 0.f);
                pp0[j] += v * w2c0[nt];
                pp1[j] += v * w2c1[nt];
            }
#pragma unroll
        for (int m = 1; m < 16; m <<= 1)
#pragma unroll
            for (int j = 0; j < 4; ++j) {
                pp0[j] += __shfl_xor(pp0[j], m);
                pp1[j] += __shfl_xor(pp1[j], m);
            }
        if (c == 0) {
#pragma unroll
            for (int j = 0; j < 4; ++j) {
                int row = r0 + kg * 4 + j;
                outp[(size_t)row * 2 + 0] = 1.f / (1.f + expf(-(pp0[j] + s0)));
                outp[(size_t)row * 2 + 1] = 1.f / (1.f + expf(-(pp1[j] + s1)));
            }
        }
    }
}

// ---- CSR build ----
__global__ __launch_bounds__(256) void hist_kernel(
    const int* __restrict__ key, int* __restrict__ cnt, int E)
{
    int e = blockIdx.x * 256 + threadIdx.x;
    if (e < E) atomicAdd(&cnt[key[e]], 1);
}

__global__ __launch_bounds__(256) void offsets_kernel(
    const int* __restrict__ cnt, int* __restrict__ off,
    int* __restrict__ total, int N)
{
    int n = blockIdx.x * 256 + threadIdx.x;
    int lane = threadIdx.x & 63;
    int v = (n < N) ? cnt[n] : 0;
    int incl = v;
#pragma unroll
    for (int d = 1; d < 64; d <<= 1) {
        int up = __shfl_up(incl, d);
        if (lane >= d) incl += up;
    }
    int wave_sum = __shfl(incl, 63);
    int base = 0;
    if (lane == 63) base = atomicAdd(total, wave_sum);
    base = __shfl(base, 63);
    if (n < N) off[n] = base + incl - v;
}

__global__ __launch_bounds__(256) void scatter_adj(
    const int* __restrict__ key, const int* __restrict__ val,
    const int* __restrict__ off, int* __restrict__ fill,
    int* __restrict__ adj, int E)
{
    int e = blockIdx.x * 256 + threadIdx.x;
    if (e < E) {
        int k = key[e];
        int p = off[k] + atomicAdd(&fill[k], 1);
        adj[p] = val[e];
    }
}

// ---- gather aggregation (bf16): Sdiv[n] = mean_e relu((RW[n]+LW[adj])*sf) ----
__global__ __launch_bounds__(256) void node_gather(
    const int* __restrict__ off, const int* __restrict__ cnt,
    const int* __restrict__ adj,
    const u16* __restrict__ RW, const u16* __restrict__ LW,
    u16* __restrict__ Sdiv, float* __restrict__ cntf,
    const float* __restrict__ sf_p, int N)
{
    int t = blockIdx.x * 256 + threadIdx.x;
    int n = t >> 5;
    if (n >= N) return;
    int lane = t & 31;
    const float sf = *sf_p;
    int start = off[n], len = cnt[n];
    uint2 ru = *(const uint2*)(RW + (size_t)n * 128 + lane * 4);
    float r0 = bf2f((u16)(ru.x & 0xffff)), r1 = bf2f((u16)(ru.x >> 16));
    float r2 = bf2f((u16)(ru.y & 0xffff)), r3 = bf2f((u16)(ru.y >> 16));
    float a0 = 0.f, a1 = 0.f, a2 = 0.f, a3 = 0.f;
    for (int i = 0; i < len; ++i) {
        int l = adj[start + i];
        uint2 lu = *(const uint2*)(LW + (size_t)l * 128 + lane * 4);
        a0 += fmaxf((r0 + bf2f((u16)(lu.x & 0xffff))) * sf, 0.f);
        a1 += fmaxf((r1 + bf2f((u16)(lu.x >> 16))) * sf, 0.f);
        a2 += fmaxf((r2 + bf2f((u16)(lu.y & 0xffff))) * sf, 0.f);
        a3 += fmaxf((r3 + bf2f((u16)(lu.y >> 16))) * sf, 0.f);
    }
    float inv = 1.f / fmaxf((float)len, 1.f);
    uint2 o;
    o.x = (unsigned)f2bf(a0 * inv) | ((unsigned)f2bf(a1 * inv) << 16);
    o.y = (unsigned)f2bf(a2 * inv) | ((unsigned)f2bf(a3 * inv) << 16);
    *(uint2*)(Sdiv + (size_t)n * 128 + lane * 4) = o;
    if (lane == 0) cntf[n] = (float)len;
}

extern "C" void kernel_launch(void* const* d_in, const int* in_sizes, int n_in,
                              void* d_out, int out_size, void* d_ws, size_t ws_size,
                              hipStream_t stream)
{
    const float* pivot = (const float*)d_in[0];
    const float* child = (const float*)d_in[1];
    const int* edges = (const int*)d_in[2];
    const int F = in_sizes[3];           // 69
    const int NP = in_sizes[0] / F;
    const int NC = in_sizes[1] / F;
    const int E = in_sizes[2] / 2;
    const int* src = edges;
    const int* dst = edges + E;

    const float *pe_shift = (const float*)d_in[3], *pe_scale = (const float*)d_in[4],
                *pe_w1 = (const float*)d_in[5], *pe_b1 = (const float*)d_in[6],
                *pe_w2 = (const float*)d_in[7], *pe_b2 = (const float*)d_in[8];
    const float *ce_shift = (const float*)d_in[9], *ce_scale = (const float*)d_in[10],
                *ce_w1 = (const float*)d_in[11], *ce_b1 = (const float*)d_in[12],
                *ce_w2 = (const float*)d_in[13], *ce_b2 = (const float*)d_in[14];
    const float *vc_wl = (const float*)d_in[15], *vc_bl = (const float*)d_in[16],
                *vc_wr = (const float*)d_in[17], *vc_sf = (const float*)d_in[18],
                *vc_wf = (const float*)d_in[19], *vc_bf = (const float*)d_in[20],
                *vc_sp = (const float*)d_in[21], *vc_wo1 = (const float*)d_in[22],
                *vc_bo1 = (const float*)d_in[23], *vc_wo2 = (const float*)d_in[24],
                *vc_bo2 = (const float*)d_in[25];
    const float *cv_wl = (const float*)d_in[26], *cv_bl = (const float*)d_in[27],
                *cv_wr = (const float*)d_in[28], *cv_sf = (const float*)d_in[29],
                *cv_wf = (const float*)d_in[30], *cv_bf = (const float*)d_in[31],
                *cv_sp = (const float*)d_in[32], *cv_wo1 = (const float*)d_in[33],
                *cv_bo1 = (const float*)d_in[34], *cv_wo2 = (const float*)d_in[35],
                *cv_bo2 = (const float*)d_in[36];
    const float *out_w1 = (const float*)d_in[37], *out_b1 = (const float*)d_in[38],
                *out_w2 = (const float*)d_in[39], *out_b2 = (const float*)d_in[40];

    // ---- workspace carve (256B aligned) ----
    char* base = (char*)d_ws;
    size_t off = 0;
    auto carve = [&](size_t bytes) {
        void* p = base + off;
        off += (bytes + 255) & ~(size_t)255;
        return p;
    };
    u16* WT = (u16*)carve((size_t)15 * 32768 * 2);
    u16* FP = (u16*)carve((size_t)NP * 96 * 2);
    u16* FC = (u16*)carve((size_t)NC * 96 * 2);
    u16* B0 = (u16*)carve((size_t)NP * 128 * 2);   // pv0
    u16* B1 = (u16*)carve((size_t)NC * 128 * 2);
    u16* B2 = (u16*)carve((size_t)NC * 128 * 2);
    u16* B3 = (u16*)carve((size_t)NC * 128 * 2);
    u16* B4 = (u16*)carve((size_t)NC * 128 * 2);
    const int NMAX = (NC > NP) ? NC : NP;
    float* cntf = (float*)carve((size_t)NMAX * 4);
    int* cnt_c = (int*)carve((size_t)(2 * NC + 2 * NP + 2) * 4);  // one memset
    int* cnt_p = cnt_c + NC;
    int* fill_c = cnt_p + NP;
    int* fill_p = fill_c + NC;
    int* totals = fill_p + NP;
    int* off_c = (int*)carve((size_t)NC * 4);
    int* off_p = (int*)carve((size_t)NP * 4);
    int* adj_c = (int*)carve((size_t)E * 4);
    int* adj_p = (int*)carve((size_t)E * 4);

    // ---- weight conversion ----
    WPack wp;
    auto setw = [&](int i, const float* s, int ks, int kd, const float* sp) {
        wp.e[i].src = s; wp.e[i].sp = sp; wp.e[i].Ksrc = ks; wp.e[i].Kdst = kd;
    };
    setw(0, pe_w1, F, 96, nullptr);   setw(1, pe_w2, 128, 128, nullptr);
    setw(2, ce_w1, F, 96, nullptr);   setw(3, ce_w2, 128, 128, nullptr);
    setw(4, vc_wl, 128, 128, nullptr); setw(5, vc_wr, 128, 128, nullptr);
    setw(6, vc_wf, 128, 128, nullptr); setw(7, vc_wo1, 256, 256, vc_sp);
    setw(8, vc_wo2, 128, 128, nullptr);
    setw(9, cv_wl, 128, 128, nullptr); setw(10, cv_wr, 128, 128, nullptr);
    setw(11, cv_wf, 128, 128, nullptr); setw(12, cv_wo1, 256, 256, cv_sp);
    setw(13, cv_wo2, 128, 128, nullptr); setw(14, out_w1, 128, 128, nullptr);
    hipLaunchKernelGGL(wconvert, dim3(15 * 128), dim3(256), 0, stream, wp, WT);
    auto wt = [&](int i) { return WT + (size_t)i * 32768; };

    // ---- feature conversion ----
    hipLaunchKernelGGL(featconv, dim3(2048), dim3(256), 0, stream,
                       pivot, pe_shift, pe_scale, FP, (long)NP * 96, F);
    hipLaunchKernelGGL(featconv, dim3(2048), dim3(256), 0, stream,
                       child, ce_shift, ce_scale, FC, (long)NC * 96, F);

    // ---- CSR build ----
    const int EB = (E + 255) / 256;
    hipMemsetAsync(cnt_c, 0, (size_t)(2 * NC + 2 * NP + 2) * 4, stream);
    hipLaunchKernelGGL(hist_kernel, dim3(EB), dim3(256), 0, stream, dst, cnt_c, E);
    hipLaunchKernelGGL(hist_kernel, dim3(EB), dim3(256), 0, stream, src, cnt_p, E);
    hipLaunchKernelGGL(offsets_kernel, dim3((NC + 255) / 256), dim3(256), 0, stream,
                       cnt_c, off_c, totals + 0, NC);
    hipLaunchKernelGGL(offsets_kernel, dim3((NP + 255) / 256), dim3(256), 0, stream,
                       cnt_p, off_p, totals + 1, NP);
    hipLaunchKernelGGL(scatter_adj, dim3(EB), dim3(256), 0, stream,
                       dst, src, off_c, fill_c, adj_c, E);
    hipLaunchKernelGGL(scatter_adj, dim3(EB), dim3(256), 0, stream,
                       src, dst, off_p, fill_p, adj_p, E);

    // ---- GEMM helpers ----
    const dim3 blk(256);
    auto grd = [](int M) {
        int items = M >> 4;
        int b = (items + 3) / 4;
        return dim3((unsigned)(b < 512 ? b : 512));
    };

    // embeddings
    gemm_rb<3, false, true, false><<<grd(NP), blk, 0, stream>>>(
        FP, nullptr, wt(0), pe_b1, nullptr, B1, NP);
    gemm_rb<4, false, true, false><<<grd(NP), blk, 0, stream>>>(
        B1, nullptr, wt(1), pe_b2, nullptr, B0, NP);            // pv0
    gemm_rb<3, false, true, false><<<grd(NC), blk, 0, stream>>>(
        FC, nullptr, wt(2), ce_b1, nullptr, B1, NC);
    gemm_rb<4, false, true, false><<<grd(NC), blk, 0, stream>>>(
        B1, nullptr, wt(3), ce_b2, nullptr, B2, NC);            // ch0

    // conv v->c (aggregate to children)
    gemm_rb<4, false, false, false><<<grd(NC), blk, 0, stream>>>(
        B2, nullptr, wt(4), vc_bl, nullptr, B1, NC);            // RW_c
    gemm_rb<4, false, false, false><<<grd(NP), blk, 0, stream>>>(
        B0, nullptr, wt(5), nullptr, nullptr, B3, NP);          // LW
    hipLaunchKernelGGL(node_gather, dim3(((size_t)NC * 32 + 255) / 256), blk, 0,
                       stream, off_c, cnt_c, adj_c, B1, B3, B4, cntf, vc_sf, NC);
    gemm_rb<4, false, false, true><<<grd(NC), blk, 0, stream>>>(
        B4, nullptr, wt(6), vc_bf, cntf, B1, NC);               // agg_c
    gemm_rb<8, true, true, false><<<grd(NC), blk, 0, stream>>>(
        B1, B2, wt(7), vc_bo1, nullptr, B3, NC);                // h_c
    gemm_rb<4, false, false, false><<<grd(NC), blk, 0, stream>>>(
        B3, nullptr, wt(8), vc_bo2, nullptr, B4, NC);           // ch1

    // conv c->v (aggregate to pivot)
    gemm_rb<4, false, false, false><<<grd(NP), blk, 0, stream>>>(
        B0, nullptr, wt(9), cv_bl, nullptr, B1, NP);            // RW_p
    gemm_rb<4, false, false, false><<<grd(NC), blk, 0, stream>>>(
        B4, nullptr, wt(10), nullptr, nullptr, B3, NC);         // LW_c
    hipLaunchKernelGGL(node_gather, dim3(((size_t)NP * 32 + 255) / 256), blk, 0,
                       stream, off_p, cnt_p, adj_p, B1, B3, B2, cntf, cv_sf, NP);
    gemm_rb<4, false, false, true><<<grd(NP), blk, 0, stream>>>(
        B2, nullptr, wt(11), cv_bf, cntf, B1, NP);              // agg_p
    gemm_rb<8, true, true, false><<<grd(NP), blk, 0, stream>>>(
        B1, B0, wt(12), cv_bo1, nullptr, B2, NP);               // h_p
    gemm_rb<4, false, false, false><<<grd(NP), blk, 0, stream>>>(
        B2, nullptr, wt(13), cv_bo2, nullptr, B1, NP);          // pv1

    // fused head
    hipLaunchKernelGGL(head_fused, grd(NP), blk, 0, stream,
                       B1, wt(14), out_b1, out_w2, out_b2, (float*)d_out, NP);
}

// Round 5
// 501.268 us; speedup vs baseline: 6.6636x; 1.0338x over previous
//
#include <hip/hip_runtime.h>
#include <math.h>

// ---------------------------------------------------------------------------
// Round 5: gather MLP doubling + GEMM prefetch-2 + merged CSR passes.
//   - node_gather2: two 16-lane halves per node walk edges stride-2 (uint4
//     row chunks) -> serial chain deg/2, half the load instructions.
//   - gemm_rb: A prefetched 2 items ahead (covers L2/HBM latency w/ 2 MFMA
//     phases at 2 waves/SIMD).
//   - hist2/scatter2: both CSR directions built in one pass over edges.
// ---------------------------------------------------------------------------

typedef unsigned short u16;
typedef __attribute__((ext_vector_type(8))) short s8v;   // 8 bf16 = 4 VGPR
typedef __attribute__((ext_vector_type(4))) float f4v;   // MFMA C/D frag

__device__ __forceinline__ float bf2f(u16 u) {
    unsigned x = ((unsigned)u) << 16;
    return __builtin_bit_cast(float, x);
}
__device__ __forceinline__ u16 f2bf(float f) {
    unsigned x = __builtin_bit_cast(unsigned, f);
    unsigned r = x + 0x7fffu + ((x >> 16) & 1u);
    return (u16)(r >> 16);
}
__device__ __forceinline__ void unpack8(uint4 u, float* f) {
    f[0] = bf2f((u16)(u.x & 0xffff)); f[1] = bf2f((u16)(u.x >> 16));
    f[2] = bf2f((u16)(u.y & 0xffff)); f[3] = bf2f((u16)(u.y >> 16));
    f[4] = bf2f((u16)(u.z & 0xffff)); f[5] = bf2f((u16)(u.z >> 16));
    f[6] = bf2f((u16)(u.w & 0xffff)); f[7] = bf2f((u16)(u.w >> 16));
}

// ---- weight conversion: fp32 [Ksrc][128] -> bf16 WT[col*Kdst + k], pad k ----
struct WEnt { const float* src; const float* sp; int Ksrc; int Kdst; };
struct WPack { WEnt e[15]; };

__global__ __launch_bounds__(256) void wconvert(WPack p, u16* __restrict__ wt)
{
    int t = blockIdx.x * 256 + threadIdx.x;
    int m = t >> 15;            // 32768 slots per matrix
    int i = t & 32767;
    WEnt en = p.e[m];
    if (i >= (en.Kdst << 7)) return;
    int k = i >> 7, col = i & 127;
    float v = 0.f;
    if (k < en.Ksrc) {
        v = en.src[k * 128 + col];
        if (en.sp && k < 128) v *= *en.sp;
    }
    wt[(size_t)m * 32768 + (size_t)col * en.Kdst + k] = f2bf(v);
}

// ---- feature conversion: fp32 [M,F] -> bf16 [M,96] with prenorm ----
__global__ __launch_bounds__(256) void featconv(
    const float* __restrict__ x, const float* __restrict__ shift,
    const float* __restrict__ scale, u16* __restrict__ y,
    long total, int F)
{
    for (long i = (long)blockIdx.x * 256 + threadIdx.x; i < total;
         i += (long)gridDim.x * 256) {
        int c = (int)(i % 96);
        long r = i / 96;
        float v = 0.f;
        if (c < F) {
            v = x[r * F + c];
            v = (v + shift[c]) * scale[c];
        }
        y[i] = f2bf(v);
    }
}

// ---- register-persistent-B GEMM: out[M,128] = act([A1|A2] @ W + bias*g) ----
template <int KS, bool HASA2, bool RELU, bool GATE>
__global__ __launch_bounds__(256) void gemm_rb(
    const u16* __restrict__ A1, const u16* __restrict__ A2,
    const u16* __restrict__ WT,      // bf16 [128][KS*32] col-major
    const float* __restrict__ bias,  // fp32 [128] or null
    const float* __restrict__ gate,  // fp32 [M] (cnt) when GATE
    u16* __restrict__ out, int M)    // M % 16 == 0
{
    constexpr int KT = KS * 32;
    constexpr int K1 = HASA2 ? 128 : KT;
    constexpr int KP = (KS > 4) ? 4 : KS;   // persisted ks blocks
    constexpr bool PF = (KS <= 4);          // A prefetch (reg budget)
    const int lane = threadIdx.x & 63;
    const int c = lane & 15;
    const int kg = lane >> 4;
    const int wid = blockIdx.x * 4 + (threadIdx.x >> 6);
    const int ws = gridDim.x * 4;
    const int items = M >> 4;

    // persist B fragments: bp[ks][nt] covers cols nt*16+c, k ks*32+kg*8..+7
    const u16* wbase = WT + (size_t)c * KT + kg * 8;
    s8v bp[KP][8];
#pragma unroll
    for (int ks = 0; ks < KP; ++ks)
#pragma unroll
        for (int nt = 0; nt < 8; ++nt)
            bp[ks][nt] = *(const s8v*)(wbase + ((size_t)nt * 16) * KT + ks * 32);

    float bc[8];
#pragma unroll
    for (int nt = 0; nt < 8; ++nt) bc[nt] = bias ? bias[nt * 16 + c] : 0.f;

    auto lda = [&](s8v* a, int item) {
        const u16* ap = A1 + (size_t)((item << 4) + c) * K1 + kg * 8;
#pragma unroll
        for (int ks = 0; ks < (HASA2 ? 4 : KS); ++ks)
            a[ks] = *(const s8v*)(ap + ks * 32);
        if (HASA2) {
            const u16* ap2 = A2 + (size_t)((item << 4) + c) * 128 + kg * 8;
#pragma unroll
            for (int ks = 0; ks < 4; ++ks) a[4 + ks] = *(const s8v*)(ap2 + ks * 32);
        }
    };

    s8v a[KS], an[KS], a2[KS];
    int item = wid;
    if (item < items) lda(a, item);
    if (PF && item + ws < items) lda(an, item + ws);
    while (item < items) {
        const int i2 = item + 2 * ws;
        if (PF && i2 < items) lda(a2, i2);

        f4v acc[8];
#pragma unroll
        for (int nt = 0; nt < 8; ++nt) acc[nt] = (f4v){0.f, 0.f, 0.f, 0.f};
#pragma unroll
        for (int ks = 0; ks < KP; ++ks)
#pragma unroll
            for (int nt = 0; nt < 8; ++nt)
                acc[nt] = __builtin_amdgcn_mfma_f32_16x16x32_bf16(a[ks], bp[ks][nt], acc[nt], 0, 0, 0);
        if (KS > KP) {
#pragma unroll
            for (int ks = KP; ks < KS; ++ks)
#pragma unroll
                for (int nt = 0; nt < 8; ++nt) {
                    s8v b = *(const s8v*)(wbase + ((size_t)nt * 16) * KT + ks * 32);
                    acc[nt] = __builtin_amdgcn_mfma_f32_16x16x32_bf16(a[ks], b, acc[nt], 0, 0, 0);
                }
        }

        const int r0 = item << 4;
        float g4[4];
#pragma unroll
        for (int j = 0; j < 4; ++j)
            g4[j] = GATE ? (gate[r0 + kg * 4 + j] > 0.f ? 1.f : 0.f) : 1.f;
#pragma unroll
        for (int nt = 0; nt < 8; ++nt)
#pragma unroll
            for (int j = 0; j < 4; ++j) {
                float v = acc[nt][j] + bc[nt] * g4[j];
                if (RELU) v = fmaxf(v, 0.f);
                out[(size_t)(r0 + kg * 4 + j) * 128 + nt * 16 + c] = f2bf(v);
            }

        if (PF) {
#pragma unroll
            for (int ks = 0; ks < KS; ++ks) { a[ks] = an[ks]; an[ks] = a2[ks]; }
        } else if (item + ws < items) {
            lda(a, item + ws);
        }
        item += ws;
    }
}

// ---- fused head: sigmoid(relu(A@W1+b1) @ w2 + b2) -> [M,2] fp32 ----
__global__ __launch_bounds__(256) void head_fused(
    const u16* __restrict__ A1, const u16* __restrict__ WT,
    const float* __restrict__ b1, const float* __restrict__ w2,
    const float* __restrict__ b2, float* __restrict__ outp, int M)
{
    constexpr int KT = 128;
    const int lane = threadIdx.x & 63;
    const int c = lane & 15;
    const int kg = lane >> 4;
    const int wid = blockIdx.x * 4 + (threadIdx.x >> 6);
    const int ws = gridDim.x * 4;
    const int items = M >> 4;

    const u16* wbase = WT + (size_t)c * KT + kg * 8;
    s8v bp[4][8];
#pragma unroll
    for (int ks = 0; ks < 4; ++ks)
#pragma unroll
        for (int nt = 0; nt < 8; ++nt)
            bp[ks][nt] = *(const s8v*)(wbase + ((size_t)nt * 16) * KT + ks * 32);

    float bc[8], w2c0[8], w2c1[8];
#pragma unroll
    for (int nt = 0; nt < 8; ++nt) {
        int col = nt * 16 + c;
        bc[nt] = b1[col];
        w2c0[nt] = w2[col * 2 + 0];
        w2c1[nt] = w2[col * 2 + 1];
    }
    const float s0 = b2[0], s1 = b2[1];

    for (int item = wid; item < items; item += ws) {
        const int r0 = item << 4;
        const u16* ap = A1 + (size_t)(r0 + c) * 128 + kg * 8;
        s8v a[4];
#pragma unroll
        for (int ks = 0; ks < 4; ++ks) a[ks] = *(const s8v*)(ap + ks * 32);

        f4v acc[8];
#pragma unroll
        for (int nt = 0; nt < 8; ++nt) acc[nt] = (f4v){0.f, 0.f, 0.f, 0.f};
#pragma unroll
        for (int ks = 0; ks < 4; ++ks)
#pragma unroll
            for (int nt = 0; nt < 8; ++nt)
                acc[nt] = __builtin_amdgcn_mfma_f32_16x16x32_bf16(a[ks], bp[ks][nt], acc[nt], 0, 0, 0);

        float pp0[4] = {0.f, 0.f, 0.f, 0.f}, pp1[4] = {0.f, 0.f, 0.f, 0.f};
#pragma unroll
        for (int nt = 0; nt < 8; ++nt)
#pragma unroll
            for (int j = 0; j < 4; ++j) {
                float v = fmaxf(acc[nt][j] + bc[nt], 0.f);
                pp0[j] += v * w2c0[nt];
                pp1[j] += v * w2c1[nt];
            }
#pragma unroll
        for (int m = 1; m < 16; m <<= 1)
#pragma unroll
            for (int j = 0; j < 4; ++j) {
                pp0[j] += __shfl_xor(pp0[j], m);
                pp1[j] += __shfl_xor(pp1[j], m);
            }
        if (c == 0) {
#pragma unroll
            for (int j = 0; j < 4; ++j) {
                int row = r0 + kg * 4 + j;
                outp[(size_t)row * 2 + 0] = 1.f / (1.f + expf(-(pp0[j] + s0)));
                outp[(size_t)row * 2 + 1] = 1.f / (1.f + expf(-(pp1[j] + s1)));
            }
        }
    }
}

// ---- CSR build (both directions in one pass) ----
__global__ __launch_bounds__(256) void hist2(
    const int* __restrict__ src, const int* __restrict__ dst,
    int* __restrict__ cnt_p, int* __restrict__ cnt_c, int E)
{
    int e = blockIdx.x * 256 + threadIdx.x;
    if (e < E) {
        atomicAdd(&cnt_p[src[e]], 1);
        atomicAdd(&cnt_c[dst[e]], 1);
    }
}

__global__ __launch_bounds__(256) void offsets_kernel(
    const int* __restrict__ cnt, int* __restrict__ off,
    int* __restrict__ total, int N)
{
    int n = blockIdx.x * 256 + threadIdx.x;
    int lane = threadIdx.x & 63;
    int v = (n < N) ? cnt[n] : 0;
    int incl = v;
#pragma unroll
    for (int d = 1; d < 64; d <<= 1) {
        int up = __shfl_up(incl, d);
        if (lane >= d) incl += up;
    }
    int wave_sum = __shfl(incl, 63);
    int base = 0;
    if (lane == 63) base = atomicAdd(total, wave_sum);
    base = __shfl(base, 63);
    if (n < N) off[n] = base + incl - v;
}

__global__ __launch_bounds__(256) void scatter2(
    const int* __restrict__ src, const int* __restrict__ dst,
    const int* __restrict__ off_p, const int* __restrict__ off_c,
    int* __restrict__ fill_p, int* __restrict__ fill_c,
    int* __restrict__ adj_p, int* __restrict__ adj_c, int E)
{
    int e = blockIdx.x * 256 + threadIdx.x;
    if (e < E) {
        int s = src[e], d = dst[e];
        adj_c[off_c[d] + atomicAdd(&fill_c[d], 1)] = s;
        adj_p[off_p[s] + atomicAdd(&fill_p[s], 1)] = d;
    }
}

// ---- gather: Sdiv[n] = mean_e relu((RW[n]+LW[adj])*sf); two 16-lane halves
//      per node walk the edge list stride-2 (uint4 16B row chunks). ----
__global__ __launch_bounds__(256) void node_gather2(
    const int* __restrict__ off, const int* __restrict__ cnt,
    const int* __restrict__ adj,
    const u16* __restrict__ RW, const u16* __restrict__ LW,
    u16* __restrict__ Sdiv, float* __restrict__ cntf,
    const float* __restrict__ sf_p, int N)
{
    int t = blockIdx.x * 256 + threadIdx.x;
    int n = t >> 5;
    if (n >= N) return;
    int l32 = t & 31;
    int c = l32 & 15;          // 16B chunk (8 bf16) within the row
    int half = l32 >> 4;       // 0/1: edge parity
    const float sf = *sf_p;
    const int start = off[n], len = cnt[n];

    float rw[8];
    unpack8(*(const uint4*)(RW + (size_t)n * 128 + c * 8), rw);
    float acc[8] = {0.f, 0.f, 0.f, 0.f, 0.f, 0.f, 0.f, 0.f};

    for (int i = half; i < len; i += 2) {
        int l = adj[start + i];
        float lw[8];
        unpack8(*(const uint4*)(LW + (size_t)l * 128 + c * 8), lw);
#pragma unroll
        for (int j = 0; j < 8; ++j)
            acc[j] += fmaxf((rw[j] + lw[j]) * sf, 0.f);
    }
#pragma unroll
    for (int j = 0; j < 8; ++j) acc[j] += __shfl_xor(acc[j], 16);

    if (half == 0) {
        float inv = 1.f / fmaxf((float)len, 1.f);
        uint4 o;
        o.x = (unsigned)f2bf(acc[0] * inv) | ((unsigned)f2bf(acc[1] * inv) << 16);
        o.y = (unsigned)f2bf(acc[2] * inv) | ((unsigned)f2bf(acc[3] * inv) << 16);
        o.z = (unsigned)f2bf(acc[4] * inv) | ((unsigned)f2bf(acc[5] * inv) << 16);
        o.w = (unsigned)f2bf(acc[6] * inv) | ((unsigned)f2bf(acc[7] * inv) << 16);
        *(uint4*)(Sdiv + (size_t)n * 128 + c * 8) = o;
        if (l32 == 0) cntf[n] = (float)len;
    }
}

extern "C" void kernel_launch(void* const* d_in, const int* in_sizes, int n_in,
                              void* d_out, int out_size, void* d_ws, size_t ws_size,
                              hipStream_t stream)
{
    const float* pivot = (const float*)d_in[0];
    const float* child = (const float*)d_in[1];
    const int* edges = (const int*)d_in[2];
    const int F = in_sizes[3];           // 69
    const int NP = in_sizes[0] / F;
    const int NC = in_sizes[1] / F;
    const int E = in_sizes[2] / 2;
    const int* src = edges;
    const int* dst = edges + E;

    const float *pe_shift = (const float*)d_in[3], *pe_scale = (const float*)d_in[4],
                *pe_w1 = (const float*)d_in[5], *pe_b1 = (const float*)d_in[6],
                *pe_w2 = (const float*)d_in[7], *pe_b2 = (const float*)d_in[8];
    const float *ce_shift = (const float*)d_in[9], *ce_scale = (const float*)d_in[10],
                *ce_w1 = (const float*)d_in[11], *ce_b1 = (const float*)d_in[12],
                *ce_w2 = (const float*)d_in[13], *ce_b2 = (const float*)d_in[14];
    const float *vc_wl = (const float*)d_in[15], *vc_bl = (const float*)d_in[16],
                *vc_wr = (const float*)d_in[17], *vc_sf = (const float*)d_in[18],
                *vc_wf = (const float*)d_in[19], *vc_bf = (const float*)d_in[20],
                *vc_sp = (const float*)d_in[21], *vc_wo1 = (const float*)d_in[22],
                *vc_bo1 = (const float*)d_in[23], *vc_wo2 = (const float*)d_in[24],
                *vc_bo2 = (const float*)d_in[25];
    const float *cv_wl = (const float*)d_in[26], *cv_bl = (const float*)d_in[27],
                *cv_wr = (const float*)d_in[28], *cv_sf = (const float*)d_in[29],
                *cv_wf = (const float*)d_in[30], *cv_bf = (const float*)d_in[31],
                *cv_sp = (const float*)d_in[32], *cv_wo1 = (const float*)d_in[33],
                *cv_bo1 = (const float*)d_in[34], *cv_wo2 = (const float*)d_in[35],
                *cv_bo2 = (const float*)d_in[36];
    const float *out_w1 = (const float*)d_in[37], *out_b1 = (const float*)d_in[38],
                *out_w2 = (const float*)d_in[39], *out_b2 = (const float*)d_in[40];

    // ---- workspace carve (256B aligned) ----
    char* base = (char*)d_ws;
    size_t off = 0;
    auto carve = [&](size_t bytes) {
        void* p = base + off;
        off += (bytes + 255) & ~(size_t)255;
        return p;
    };
    u16* WT = (u16*)carve((size_t)15 * 32768 * 2);
    u16* FP = (u16*)carve((size_t)NP * 96 * 2);
    u16* FC = (u16*)carve((size_t)NC * 96 * 2);
    u16* B0 = (u16*)carve((size_t)NP * 128 * 2);   // pv0
    u16* B1 = (u16*)carve((size_t)NC * 128 * 2);
    u16* B2 = (u16*)carve((size_t)NC * 128 * 2);
    u16* B3 = (u16*)carve((size_t)NC * 128 * 2);
    u16* B4 = (u16*)carve((size_t)NC * 128 * 2);
    const int NMAX = (NC > NP) ? NC : NP;
    float* cntf = (float*)carve((size_t)NMAX * 4);
    int* cnt_c = (int*)carve((size_t)(2 * NC + 2 * NP + 2) * 4);  // one memset
    int* cnt_p = cnt_c + NC;
    int* fill_c = cnt_p + NP;
    int* fill_p = fill_c + NC;
    int* totals = fill_p + NP;
    int* off_c = (int*)carve((size_t)NC * 4);
    int* off_p = (int*)carve((size_t)NP * 4);
    int* adj_c = (int*)carve((size_t)E * 4);
    int* adj_p = (int*)carve((size_t)E * 4);

    // ---- weight conversion ----
    WPack wp;
    auto setw = [&](int i, const float* s, int ks, int kd, const float* sp) {
        wp.e[i].src = s; wp.e[i].sp = sp; wp.e[i].Ksrc = ks; wp.e[i].Kdst = kd;
    };
    setw(0, pe_w1, F, 96, nullptr);   setw(1, pe_w2, 128, 128, nullptr);
    setw(2, ce_w1, F, 96, nullptr);   setw(3, ce_w2, 128, 128, nullptr);
    setw(4, vc_wl, 128, 128, nullptr); setw(5, vc_wr, 128, 128, nullptr);
    setw(6, vc_wf, 128, 128, nullptr); setw(7, vc_wo1, 256, 256, vc_sp);
    setw(8, vc_wo2, 128, 128, nullptr);
    setw(9, cv_wl, 128, 128, nullptr); setw(10, cv_wr, 128, 128, nullptr);
    setw(11, cv_wf, 128, 128, nullptr); setw(12, cv_wo1, 256, 256, cv_sp);
    setw(13, cv_wo2, 128, 128, nullptr); setw(14, out_w1, 128, 128, nullptr);
    hipLaunchKernelGGL(wconvert, dim3(15 * 128), dim3(256), 0, stream, wp, WT);
    auto wt = [&](int i) { return WT + (size_t)i * 32768; };

    // ---- feature conversion ----
    hipLaunchKernelGGL(featconv, dim3(2048), dim3(256), 0, stream,
                       pivot, pe_shift, pe_scale, FP, (long)NP * 96, F);
    hipLaunchKernelGGL(featconv, dim3(2048), dim3(256), 0, stream,
                       child, ce_shift, ce_scale, FC, (long)NC * 96, F);

    // ---- CSR build ----
    const int EB = (E + 255) / 256;
    hipMemsetAsync(cnt_c, 0, (size_t)(2 * NC + 2 * NP + 2) * 4, stream);
    hipLaunchKernelGGL(hist2, dim3(EB), dim3(256), 0, stream,
                       src, dst, cnt_p, cnt_c, E);
    hipLaunchKernelGGL(offsets_kernel, dim3((NC + 255) / 256), dim3(256), 0, stream,
                       cnt_c, off_c, totals + 0, NC);
    hipLaunchKernelGGL(offsets_kernel, dim3((NP + 255) / 256), dim3(256), 0, stream,
                       cnt_p, off_p, totals + 1, NP);
    hipLaunchKernelGGL(scatter2, dim3(EB), dim3(256), 0, stream,
                       src, dst, off_p, off_c, fill_p, fill_c, adj_p, adj_c, E);

    // ---- GEMM helpers ----
    const dim3 blk(256);
    auto grd = [](int M) {
        int items = M >> 4;
        int b = (items + 3) / 4;
        return dim3((unsigned)(b < 512 ? b : 512));
    };

    // embeddings
    gemm_rb<3, false, true, false><<<grd(NP), blk, 0, stream>>>(
        FP, nullptr, wt(0), pe_b1, nullptr, B1, NP);
    gemm_rb<4, false, true, false><<<grd(NP), blk, 0, stream>>>(
        B1, nullptr, wt(1), pe_b2, nullptr, B0, NP);            // pv0
    gemm_rb<3, false, true, false><<<grd(NC), blk, 0, stream>>>(
        FC, nullptr, wt(2), ce_b1, nullptr, B1, NC);
    gemm_rb<4, false, true, false><<<grd(NC), blk, 0, stream>>>(
        B1, nullptr, wt(3), ce_b2, nullptr, B2, NC);            // ch0

    // conv v->c (aggregate to children)
    gemm_rb<4, false, false, false><<<grd(NC), blk, 0, stream>>>(
        B2, nullptr, wt(4), vc_bl, nullptr, B1, NC);            // RW_c
    gemm_rb<4, false, false, false><<<grd(NP), blk, 0, stream>>>(
        B0, nullptr, wt(5), nullptr, nullptr, B3, NP);          // LW
    hipLaunchKernelGGL(node_gather2, dim3(((size_t)NC * 32 + 255) / 256), blk, 0,
                       stream, off_c, cnt_c, adj_c, B1, B3, B4, cntf, vc_sf, NC);
    gemm_rb<4, false, false, true><<<grd(NC), blk, 0, stream>>>(
        B4, nullptr, wt(6), vc_bf, cntf, B1, NC);               // agg_c
    gemm_rb<8, true, true, false><<<grd(NC), blk, 0, stream>>>(
        B1, B2, wt(7), vc_bo1, nullptr, B3, NC);                // h_c
    gemm_rb<4, false, false, false><<<grd(NC), blk, 0, stream>>>(
        B3, nullptr, wt(8), vc_bo2, nullptr, B4, NC);           // ch1

    // conv c->v (aggregate to pivot)
    gemm_rb<4, false, false, false><<<grd(NP), blk, 0, stream>>>(
        B0, nullptr, wt(9), cv_bl, nullptr, B1, NP);            // RW_p
    gemm_rb<4, false, false, false><<<grd(NC), blk, 0, stream>>>(
        B4, nullptr, wt(10), nullptr, nullptr, B3, NC);         // LW_c
    hipLaunchKernelGGL(node_gather2, dim3(((size_t)NP * 32 + 255) / 256), blk, 0,
                       stream, off_p, cnt_p, adj_p, B1, B3, B2, cntf, cv_sf, NP);
    gemm_rb<4, false, false, true><<<grd(NP), blk, 0, stream>>>(
        B2, nullptr, wt(11), cv_bf, cntf, B1, NP);              // agg_p
    gemm_rb<8, true, true, false><<<grd(NP), blk, 0, stream>>>(
        B1, B0, wt(12), cv_bo1, nullptr, B2, NP);               // h_p
    gemm_rb<4, false, false, false><<<grd(NP), blk, 0, stream>>>(
        B2, nullptr, wt(13), cv_bo2, nullptr, B1, NP);          // pv1

    // fused head
    hipLaunchKernelGGL(head_fused, grd(NP), blk, 0, stream,
                       B1, wt(14), out_b1, out_w2, out_b2, (float*)d_out, NP);
}

// Round 6
// 459.272 us; speedup vs baseline: 7.2729x; 1.0914x over previous
//
#include <hip/hip_runtime.h>
#include <math.h>

// ---------------------------------------------------------------------------
// Round 6: algebraic folding of linear GEMM chains.
//   agg fold : h = relu(Sdiv@(sp*wf@wo1t) + ch0@wo1b + bo1 + gate*sp*(bf@wo1t))
//   ch1 fold : LW_c = h_c@(vc_wo2@cv_wr) + vc_bo2@cv_wr
//   pv1 fold : head input = h_p, W1' = cv_wo2@out_w1, b1' = cv_bo2@out_w1+ob1
//   smallmm/vecpre precompute the folded products on device (fp32, ~8 us).
//   GEMM dispatches 15 -> 10. Scatter/gather/CSR unchanged (next round).
// ---------------------------------------------------------------------------

typedef unsigned short u16;
typedef __attribute__((ext_vector_type(8))) short s8v;   // 8 bf16 = 4 VGPR
typedef __attribute__((ext_vector_type(4))) float f4v;   // MFMA C/D frag

__device__ __forceinline__ float bf2f(u16 u) {
    unsigned x = ((unsigned)u) << 16;
    return __builtin_bit_cast(float, x);
}
__device__ __forceinline__ u16 f2bf(float f) {
    unsigned x = __builtin_bit_cast(unsigned, f);
    unsigned r = x + 0x7fffu + ((x >> 16) & 1u);
    return (u16)(r >> 16);
}
__device__ __forceinline__ void unpack8(uint4 u, float* f) {
    f[0] = bf2f((u16)(u.x & 0xffff)); f[1] = bf2f((u16)(u.x >> 16));
    f[2] = bf2f((u16)(u.y & 0xffff)); f[3] = bf2f((u16)(u.y >> 16));
    f[4] = bf2f((u16)(u.z & 0xffff)); f[5] = bf2f((u16)(u.z >> 16));
    f[6] = bf2f((u16)(u.w & 0xffff)); f[7] = bf2f((u16)(u.w >> 16));
}

// ---- small fp32 128x128 matmuls for folded weights ----
struct SmEnt { const float* A; const float* B; const float* s; };
struct SmPack { SmEnt e[4]; };

__global__ __launch_bounds__(256) void smallmm(SmPack p, float* __restrict__ out)
{
    int t = blockIdx.x * 256 + threadIdx.x;
    int m = t >> 14;            // 16384 outputs per product
    int o = t & 16383;
    int i = o >> 7, j = o & 127;
    SmEnt en = p.e[m];
    float acc = 0.f;
#pragma unroll 4
    for (int k = 0; k < 128; ++k) acc += en.A[i * 128 + k] * en.B[k * 128 + j];
    if (en.s) acc *= *en.s;
    out[(size_t)m * 16384 + o] = acc;
}

// folded bias vectors: [0]=sp_vc*(vc_bf@vc_wo1t), [1]=sp_cv*(cv_bf@cv_wo1t),
//                      [2]=vc_bo2@cv_wr, [3]=cv_bo2@out_w1+out_b1
__global__ void vecpre(
    const float* vc_bf, const float* vc_wo1, const float* vc_sp,
    const float* cv_bf, const float* cv_wo1, const float* cv_sp,
    const float* vc_bo2, const float* cv_wr,
    const float* cv_bo2, const float* out_w1, const float* out_b1,
    float* __restrict__ vout)
{
    int j = threadIdx.x;
    if (j >= 128) return;
    float a0 = 0.f, a1 = 0.f, a2 = 0.f, a3 = 0.f;
    for (int k = 0; k < 128; ++k) {
        a0 += vc_bf[k] * vc_wo1[k * 128 + j];
        a1 += cv_bf[k] * cv_wo1[k * 128 + j];
        a2 += vc_bo2[k] * cv_wr[k * 128 + j];
        a3 += cv_bo2[k] * out_w1[k * 128 + j];
    }
    vout[j] = a0 * (*vc_sp);
    vout[128 + j] = a1 * (*cv_sp);
    vout[256 + j] = a2;
    vout[384 + j] = a3 + out_b1[j];
}

// ---- weight conversion: fp32 [Ksrc][128] -> bf16 WT[col*Kdst + k], pad k ----
struct WEnt { const float* src; int Ksrc; int Kdst; };
struct WPack { WEnt e[14]; };

__global__ __launch_bounds__(256) void wconvert(WPack p, u16* __restrict__ wt)
{
    int t = blockIdx.x * 256 + threadIdx.x;
    int m = t >> 15;            // 32768 slots per matrix
    int i = t & 32767;
    WEnt en = p.e[m];
    if (i >= (en.Kdst << 7)) return;
    int k = i >> 7, col = i & 127;
    float v = (k < en.Ksrc) ? en.src[k * 128 + col] : 0.f;
    wt[(size_t)m * 32768 + (size_t)col * en.Kdst + k] = f2bf(v);
}

// ---- feature conversion: fp32 [M,F] -> bf16 [M,96] with prenorm ----
__global__ __launch_bounds__(256) void featconv(
    const float* __restrict__ x, const float* __restrict__ shift,
    const float* __restrict__ scale, u16* __restrict__ y,
    long total, int F)
{
    for (long i = (long)blockIdx.x * 256 + threadIdx.x; i < total;
         i += (long)gridDim.x * 256) {
        int c = (int)(i % 96);
        long r = i / 96;
        float v = 0.f;
        if (c < F) {
            v = x[r * F + c];
            v = (v + shift[c]) * scale[c];
        }
        y[i] = f2bf(v);
    }
}

// ---- register-persistent-B GEMM ----
// out[M,128] = act( A1@WT1 (+ A2@WT2) + bias0 + gate*bias1 )
template <int KS1, bool HASA2, bool RELU, bool GATE>
__global__ __launch_bounds__(256) void gemm_rb(
    const u16* __restrict__ A1, const u16* __restrict__ A2,
    const u16* __restrict__ WT1,     // bf16 [128][KS1*32]
    const u16* __restrict__ WT2,     // bf16 [128][128] (when HASA2)
    const float* __restrict__ bias0, // fp32 [128] or null
    const float* __restrict__ bias1, // fp32 [128] or null (gated)
    const float* __restrict__ gate,  // fp32 [M] (cnt) when GATE
    u16* __restrict__ out, int M)    // M % 16 == 0
{
    constexpr int K1 = KS1 * 32;
    constexpr bool PF = !HASA2;             // prefetch when regs allow
    constexpr int AS = KS1 + (HASA2 ? 4 : 0);
    const int lane = threadIdx.x & 63;
    const int c = lane & 15;
    const int kg = lane >> 4;
    const int wid = blockIdx.x * 4 + (threadIdx.x >> 6);
    const int ws = gridDim.x * 4;
    const int items = M >> 4;

    // persist WT1 fragments
    const u16* wbase = WT1 + (size_t)c * K1 + kg * 8;
    s8v bp[KS1][8];
#pragma unroll
    for (int ks = 0; ks < KS1; ++ks)
#pragma unroll
        for (int nt = 0; nt < 8; ++nt)
            bp[ks][nt] = *(const s8v*)(wbase + ((size_t)nt * 16) * K1 + ks * 32);

    const u16* wbase2 = HASA2 ? (WT2 + (size_t)c * 128 + kg * 8) : nullptr;

    float bc0[8], bc1[8];
#pragma unroll
    for (int nt = 0; nt < 8; ++nt) {
        bc0[nt] = bias0 ? bias0[nt * 16 + c] : 0.f;
        bc1[nt] = (GATE && bias1) ? bias1[nt * 16 + c] : 0.f;
    }

    auto lda = [&](s8v* a, int item) {
        const u16* ap = A1 + (size_t)((item << 4) + c) * K1 + kg * 8;
#pragma unroll
        for (int ks = 0; ks < KS1; ++ks) a[ks] = *(const s8v*)(ap + ks * 32);
        if (HASA2) {
            const u16* ap2 = A2 + (size_t)((item << 4) + c) * 128 + kg * 8;
#pragma unroll
            for (int ks = 0; ks < 4; ++ks) a[KS1 + ks] = *(const s8v*)(ap2 + ks * 32);
        }
    };

    s8v a[AS], an[AS], a2[AS];
    int item = wid;
    if (item < items) lda(a, item);
    if (PF && item + ws < items) lda(an, item + ws);
    while (item < items) {
        const int i2 = item + 2 * ws;
        if (PF && i2 < items) lda(a2, i2);

        f4v acc[8];
#pragma unroll
        for (int nt = 0; nt < 8; ++nt) acc[nt] = (f4v){0.f, 0.f, 0.f, 0.f};
#pragma unroll
        for (int ks = 0; ks < KS1; ++ks)
#pragma unroll
            for (int nt = 0; nt < 8; ++nt)
                acc[nt] = __builtin_amdgcn_mfma_f32_16x16x32_bf16(a[ks], bp[ks][nt], acc[nt], 0, 0, 0);
        if (HASA2) {
#pragma unroll
            for (int ks = 0; ks < 4; ++ks)
#pragma unroll
                for (int nt = 0; nt < 8; ++nt) {
                    s8v b = *(const s8v*)(wbase2 + ((size_t)nt * 16) * 128 + ks * 32);
                    acc[nt] = __builtin_amdgcn_mfma_f32_16x16x32_bf16(a[KS1 + ks], b, acc[nt], 0, 0, 0);
                }
        }

        const int r0 = item << 4;
        float g4[4];
#pragma unroll
        for (int j = 0; j < 4; ++j)
            g4[j] = GATE ? (gate[r0 + kg * 4 + j] > 0.f ? 1.f : 0.f) : 0.f;
#pragma unroll
        for (int nt = 0; nt < 8; ++nt)
#pragma unroll
            for (int j = 0; j < 4; ++j) {
                float v = acc[nt][j] + bc0[nt] + g4[j] * bc1[nt];
                if (RELU) v = fmaxf(v, 0.f);
                out[(size_t)(r0 + kg * 4 + j) * 128 + nt * 16 + c] = f2bf(v);
            }

        if (PF) {
#pragma unroll
            for (int ks = 0; ks < AS; ++ks) { a[ks] = an[ks]; an[ks] = a2[ks]; }
        } else if (item + ws < items) {
            lda(a, item + ws);
        }
        item += ws;
    }
}

// ---- fused head: sigmoid(relu(A@W1+b1) @ w2 + b2) -> [M,2] fp32 ----
__global__ __launch_bounds__(256) void head_fused(
    const u16* __restrict__ A1, const u16* __restrict__ WT,
    const float* __restrict__ b1, const float* __restrict__ w2,
    const float* __restrict__ b2, float* __restrict__ outp, int M)
{
    constexpr int KT = 128;
    const int lane = threadIdx.x & 63;
    const int c = lane & 15;
    const int kg = lane >> 4;
    const int wid = blockIdx.x * 4 + (threadIdx.x >> 6);
    const int ws = gridDim.x * 4;
    const int items = M >> 4;

    const u16* wbase = WT + (size_t)c * KT + kg * 8;
    s8v bp[4][8];
#pragma unroll
    for (int ks = 0; ks < 4; ++ks)
#pragma unroll
        for (int nt = 0; nt < 8; ++nt)
            bp[ks][nt] = *(const s8v*)(wbase + ((size_t)nt * 16) * KT + ks * 32);

    float bc[8], w2c0[8], w2c1[8];
#pragma unroll
    for (int nt = 0; nt < 8; ++nt) {
        int col = nt * 16 + c;
        bc[nt] = b1[col];
        w2c0[nt] = w2[col * 2 + 0];
        w2c1[nt] = w2[col * 2 + 1];
    }
    const float s0 = b2[0], s1 = b2[1];

    for (int item = wid; item < items; item += ws) {
        const int r0 = item << 4;
        const u16* ap = A1 + (size_t)(r0 + c) * 128 + kg * 8;
        s8v a[4];
#pragma unroll
        for (int ks = 0; ks < 4; ++ks) a[ks] = *(const s8v*)(ap + ks * 32);

        f4v acc[8];
#pragma unroll
        for (int nt = 0; nt < 8; ++nt) acc[nt] = (f4v){0.f, 0.f, 0.f, 0.f};
#pragma unroll
        for (int ks = 0; ks < 4; ++ks)
#pragma unroll
            for (int nt = 0; nt < 8; ++nt)
                acc[nt] = __builtin_amdgcn_mfma_f32_16x16x32_bf16(a[ks], bp[ks][nt], acc[nt], 0, 0, 0);

        float pp0[4] = {0.f, 0.f, 0.f, 0.f}, pp1[4] = {0.f, 0.f, 0.f, 0.f};
#pragma unroll
        for (int nt = 0; nt < 8; ++nt)
#pragma unroll
            for (int j = 0; j < 4; ++j) {
                float v = fmaxf(acc[nt][j] + bc[nt], 0.f);
                pp0[j] += v * w2c0[nt];
                pp1[j] += v * w2c1[nt];
            }
#pragma unroll
        for (int m = 1; m < 16; m <<= 1)
#pragma unroll
            for (int j = 0; j < 4; ++j) {
                pp0[j] += __shfl_xor(pp0[j], m);
                pp1[j] += __shfl_xor(pp1[j], m);
            }
        if (c == 0) {
#pragma unroll
            for (int j = 0; j < 4; ++j) {
                int row = r0 + kg * 4 + j;
                outp[(size_t)row * 2 + 0] = 1.f / (1.f + expf(-(pp0[j] + s0)));
                outp[(size_t)row * 2 + 1] = 1.f / (1.f + expf(-(pp1[j] + s1)));
            }
        }
    }
}

// ---- CSR build (both directions in one pass) ----
__global__ __launch_bounds__(256) void hist2(
    const int* __restrict__ src, const int* __restrict__ dst,
    int* __restrict__ cnt_p, int* __restrict__ cnt_c, int E)
{
    int e = blockIdx.x * 256 + threadIdx.x;
    if (e < E) {
        atomicAdd(&cnt_p[src[e]], 1);
        atomicAdd(&cnt_c[dst[e]], 1);
    }
}

__global__ __launch_bounds__(256) void offsets_kernel(
    const int* __restrict__ cnt, int* __restrict__ off,
    int* __restrict__ total, int N)
{
    int n = blockIdx.x * 256 + threadIdx.x;
    int lane = threadIdx.x & 63;
    int v = (n < N) ? cnt[n] : 0;
    int incl = v;
#pragma unroll
    for (int d = 1; d < 64; d <<= 1) {
        int up = __shfl_up(incl, d);
        if (lane >= d) incl += up;
    }
    int wave_sum = __shfl(incl, 63);
    int base = 0;
    if (lane == 63) base = atomicAdd(total, wave_sum);
    base = __shfl(base, 63);
    if (n < N) off[n] = base + incl - v;
}

__global__ __launch_bounds__(256) void scatter2(
    const int* __restrict__ src, const int* __restrict__ dst,
    const int* __restrict__ off_p, const int* __restrict__ off_c,
    int* __restrict__ fill_p, int* __restrict__ fill_c,
    int* __restrict__ adj_p, int* __restrict__ adj_c, int E)
{
    int e = blockIdx.x * 256 + threadIdx.x;
    if (e < E) {
        int s = src[e], d = dst[e];
        adj_c[off_c[d] + atomicAdd(&fill_c[d], 1)] = s;
        adj_p[off_p[s] + atomicAdd(&fill_p[s], 1)] = d;
    }
}

// ---- gather: Sdiv[n] = mean_e relu((RW[n]+LW[adj])*sf) ----
__global__ __launch_bounds__(256) void node_gather2(
    const int* __restrict__ off, const int* __restrict__ cnt,
    const int* __restrict__ adj,
    const u16* __restrict__ RW, const u16* __restrict__ LW,
    u16* __restrict__ Sdiv, float* __restrict__ cntf,
    const float* __restrict__ sf_p, int N)
{
    int t = blockIdx.x * 256 + threadIdx.x;
    int n = t >> 5;
    if (n >= N) return;
    int l32 = t & 31;
    int c = l32 & 15;          // 16B chunk (8 bf16) within the row
    int half = l32 >> 4;       // 0/1: edge parity
    const float sf = *sf_p;
    const int start = off[n], len = cnt[n];

    float rw[8];
    unpack8(*(const uint4*)(RW + (size_t)n * 128 + c * 8), rw);
    float acc[8] = {0.f, 0.f, 0.f, 0.f, 0.f, 0.f, 0.f, 0.f};

    for (int i = half; i < len; i += 2) {
        int l = adj[start + i];
        float lw[8];
        unpack8(*(const uint4*)(LW + (size_t)l * 128 + c * 8), lw);
#pragma unroll
        for (int j = 0; j < 8; ++j)
            acc[j] += fmaxf((rw[j] + lw[j]) * sf, 0.f);
    }
#pragma unroll
    for (int j = 0; j < 8; ++j) acc[j] += __shfl_xor(acc[j], 16);

    if (half == 0) {
        float inv = 1.f / fmaxf((float)len, 1.f);
        uint4 o;
        o.x = (unsigned)f2bf(acc[0] * inv) | ((unsigned)f2bf(acc[1] * inv) << 16);
        o.y = (unsigned)f2bf(acc[2] * inv) | ((unsigned)f2bf(acc[3] * inv) << 16);
        o.z = (unsigned)f2bf(acc[4] * inv) | ((unsigned)f2bf(acc[5] * inv) << 16);
        o.w = (unsigned)f2bf(acc[6] * inv) | ((unsigned)f2bf(acc[7] * inv) << 16);
        *(uint4*)(Sdiv + (size_t)n * 128 + c * 8) = o;
        if (l32 == 0) cntf[n] = (float)len;
    }
}

extern "C" void kernel_launch(void* const* d_in, const int* in_sizes, int n_in,
                              void* d_out, int out_size, void* d_ws, size_t ws_size,
                              hipStream_t stream)
{
    const float* pivot = (const float*)d_in[0];
    const float* child = (const float*)d_in[1];
    const int* edges = (const int*)d_in[2];
    const int F = in_sizes[3];           // 69
    const int NP = in_sizes[0] / F;
    const int NC = in_sizes[1] / F;
    const int E = in_sizes[2] / 2;
    const int* src = edges;
    const int* dst = edges + E;

    const float *pe_shift = (const float*)d_in[3], *pe_scale = (const float*)d_in[4],
                *pe_w1 = (const float*)d_in[5], *pe_b1 = (const float*)d_in[6],
                *pe_w2 = (const float*)d_in[7], *pe_b2 = (const float*)d_in[8];
    const float *ce_shift = (const float*)d_in[9], *ce_scale = (const float*)d_in[10],
                *ce_w1 = (const float*)d_in[11], *ce_b1 = (const float*)d_in[12],
                *ce_w2 = (const float*)d_in[13], *ce_b2 = (const float*)d_in[14];
    const float *vc_wl = (const float*)d_in[15], *vc_bl = (const float*)d_in[16],
                *vc_wr = (const float*)d_in[17], *vc_sf = (const float*)d_in[18],
                *vc_wf = (const float*)d_in[19], *vc_bf = (const float*)d_in[20],
                *vc_sp = (const float*)d_in[21], *vc_wo1 = (const float*)d_in[22],
                *vc_bo1 = (const float*)d_in[23], *vc_wo2 = (const float*)d_in[24],
                *vc_bo2 = (const float*)d_in[25];
    const float *cv_wl = (const float*)d_in[26], *cv_bl = (const float*)d_in[27],
                *cv_wr = (const float*)d_in[28], *cv_sf = (const float*)d_in[29],
                *cv_wf = (const float*)d_in[30], *cv_bf = (const float*)d_in[31],
                *cv_sp = (const float*)d_in[32], *cv_wo1 = (const float*)d_in[33],
                *cv_bo1 = (const float*)d_in[34], *cv_wo2 = (const float*)d_in[35],
                *cv_bo2 = (const float*)d_in[36];
    const float *out_w1 = (const float*)d_in[37], *out_b1 = (const float*)d_in[38],
                *out_w2 = (const float*)d_in[39], *out_b2 = (const float*)d_in[40];

    // ---- workspace carve (256B aligned) ----
    char* base = (char*)d_ws;
    size_t off = 0;
    auto carve = [&](size_t bytes) {
        void* p = base + off;
        off += (bytes + 255) & ~(size_t)255;
        return p;
    };
    float* Wsc = (float*)carve((size_t)4 * 16384 * 4);   // folded fp32 products
    float* Vsc = (float*)carve((size_t)4 * 128 * 4);     // folded bias vectors
    u16* WT = (u16*)carve((size_t)14 * 32768 * 2);
    u16* FP = (u16*)carve((size_t)NP * 96 * 2);
    u16* FC = (u16*)carve((size_t)NC * 96 * 2);
    u16* B0 = (u16*)carve((size_t)NP * 128 * 2);   // pv0
    u16* B1 = (u16*)carve((size_t)NC * 128 * 2);
    u16* B2 = (u16*)carve((size_t)NC * 128 * 2);
    u16* B3 = (u16*)carve((size_t)NC * 128 * 2);
    u16* B4 = (u16*)carve((size_t)NC * 128 * 2);
    const int NMAX = (NC > NP) ? NC : NP;
    float* cntf = (float*)carve((size_t)NMAX * 4);
    int* cnt_c = (int*)carve((size_t)(2 * NC + 2 * NP + 2) * 4);  // one memset
    int* cnt_p = cnt_c + NC;
    int* fill_c = cnt_p + NP;
    int* fill_p = fill_c + NC;
    int* totals = fill_p + NP;
    int* off_c = (int*)carve((size_t)NC * 4);
    int* off_p = (int*)carve((size_t)NP * 4);
    int* adj_c = (int*)carve((size_t)E * 4);
    int* adj_p = (int*)carve((size_t)E * 4);

    // ---- folded weight precompute (fp32) ----
    SmPack sp;
    sp.e[0] = {vc_wf, vc_wo1, vc_sp};            // Wfo_vc = sp*(wf@wo1t)
    sp.e[1] = {cv_wf, cv_wo1, cv_sp};            // Wfo_cv
    sp.e[2] = {vc_wo2, cv_wr, nullptr};          // Wx = vc_wo2@cv_wr
    sp.e[3] = {cv_wo2, out_w1, nullptr};         // Wh = cv_wo2@out_w1
    hipLaunchKernelGGL(smallmm, dim3(256), dim3(256), 0, stream, sp, Wsc);
    hipLaunchKernelGGL(vecpre, dim3(1), dim3(128), 0, stream,
                       vc_bf, vc_wo1, vc_sp, cv_bf, cv_wo1, cv_sp,
                       vc_bo2, cv_wr, cv_bo2, out_w1, out_b1, Vsc);
    const float* cvec_vc = Vsc;
    const float* cvec_cv = Vsc + 128;
    const float* cx = Vsc + 256;
    const float* bh = Vsc + 384;

    // ---- weight conversion ----
    WPack wp;
    auto setw = [&](int i, const float* s, int ks, int kd) {
        wp.e[i].src = s; wp.e[i].Ksrc = ks; wp.e[i].Kdst = kd;
    };
    setw(0, pe_w1, F, 96);            setw(1, pe_w2, 128, 128);
    setw(2, ce_w1, F, 96);            setw(3, ce_w2, 128, 128);
    setw(4, vc_wl, 128, 128);         setw(5, vc_wr, 128, 128);
    setw(6, Wsc + 0 * 16384, 128, 128);       // Wfo_vc
    setw(7, vc_wo1 + 128 * 128, 128, 128);    // vc wo1 bottom (ch0 part)
    setw(8, Wsc + 2 * 16384, 128, 128);       // Wx
    setw(9, cv_wl, 128, 128);         setw(10, cv_wr, 128, 128);
    setw(11, Wsc + 1 * 16384, 128, 128);      // Wfo_cv
    setw(12, cv_wo1 + 128 * 128, 128, 128);   // cv wo1 bottom (pv0 part)
    setw(13, Wsc + 3 * 16384, 128, 128);      // Wh
    hipLaunchKernelGGL(wconvert, dim3(14 * 128), dim3(256), 0, stream, wp, WT);
    auto wt = [&](int i) { return WT + (size_t)i * 32768; };

    // ---- feature conversion ----
    hipLaunchKernelGGL(featconv, dim3(2048), dim3(256), 0, stream,
                       pivot, pe_shift, pe_scale, FP, (long)NP * 96, F);
    hipLaunchKernelGGL(featconv, dim3(2048), dim3(256), 0, stream,
                       child, ce_shift, ce_scale, FC, (long)NC * 96, F);

    // ---- CSR build ----
    const int EB = (E + 255) / 256;
    hipMemsetAsync(cnt_c, 0, (size_t)(2 * NC + 2 * NP + 2) * 4, stream);
    hipLaunchKernelGGL(hist2, dim3(EB), dim3(256), 0, stream,
                       src, dst, cnt_p, cnt_c, E);
    hipLaunchKernelGGL(offsets_kernel, dim3((NC + 255) / 256), dim3(256), 0, stream,
                       cnt_c, off_c, totals + 0, NC);
    hipLaunchKernelGGL(offsets_kernel, dim3((NP + 255) / 256), dim3(256), 0, stream,
                       cnt_p, off_p, totals + 1, NP);
    hipLaunchKernelGGL(scatter2, dim3(EB), dim3(256), 0, stream,
                       src, dst, off_p, off_c, fill_p, fill_c, adj_p, adj_c, E);

    // ---- GEMM pipeline ----
    const dim3 blk(256);
    auto grd = [](int M) {
        int items = M >> 4;
        int b = (items + 3) / 4;
        return dim3((unsigned)(b < 512 ? b : 512));
    };

    // embeddings
    gemm_rb<3, false, true, false><<<grd(NP), blk, 0, stream>>>(
        FP, nullptr, wt(0), nullptr, pe_b1, nullptr, nullptr, B1, NP);
    gemm_rb<4, false, true, false><<<grd(NP), blk, 0, stream>>>(
        B1, nullptr, wt(1), nullptr, pe_b2, nullptr, nullptr, B0, NP);   // pv0
    gemm_rb<3, false, true, false><<<grd(NC), blk, 0, stream>>>(
        FC, nullptr, wt(2), nullptr, ce_b1, nullptr, nullptr, B1, NC);
    gemm_rb<4, false, true, false><<<grd(NC), blk, 0, stream>>>(
        B1, nullptr, wt(3), nullptr, ce_b2, nullptr, nullptr, B2, NC);   // ch0

    // conv v->c (aggregate to children)
    gemm_rb<4, false, false, false><<<grd(NC), blk, 0, stream>>>(
        B2, nullptr, wt(4), nullptr, vc_bl, nullptr, nullptr, B1, NC);   // RW_c
    gemm_rb<4, false, false, false><<<grd(NP), blk, 0, stream>>>(
        B0, nullptr, wt(5), nullptr, nullptr, nullptr, nullptr, B3, NP); // LW_v
    hipLaunchKernelGGL(node_gather2, dim3(((size_t)NC * 32 + 255) / 256), blk, 0,
                       stream, off_c, cnt_c, adj_c, B1, B3, B4, cntf, vc_sf, NC);
    // h_c = relu(Sdiv@Wfo_vc + ch0@wo1b + bo1 + gate*cvec)
    gemm_rb<4, true, true, true><<<grd(NC), blk, 0, stream>>>(
        B4, B2, wt(6), wt(7), vc_bo1, cvec_vc, cntf, B1, NC);            // h_c
    gemm_rb<4, false, false, false><<<grd(NC), blk, 0, stream>>>(
        B1, nullptr, wt(8), nullptr, cx, nullptr, nullptr, B3, NC);      // LW_c

    // conv c->v (aggregate to pivot)
    gemm_rb<4, false, false, false><<<grd(NP), blk, 0, stream>>>(
        B0, nullptr, wt(9), nullptr, cv_bl, nullptr, nullptr, B2, NP);   // RW_p
    hipLaunchKernelGGL(node_gather2, dim3(((size_t)NP * 32 + 255) / 256), blk, 0,
                       stream, off_p, cnt_p, adj_p, B2, B3, B4, cntf, cv_sf, NP);
    // h_p = relu(Sdiv@Wfo_cv + pv0@wo1b + bo1 + gate*cvec)
    gemm_rb<4, true, true, true><<<grd(NP), blk, 0, stream>>>(
        B4, B0, wt(11), wt(12), cv_bo1, cvec_cv, cntf, B1, NP);          // h_p

    // fused head on h_p with folded W1'=Wh, b1'=bh
    hipLaunchKernelGGL(head_fused, grd(NP), blk, 0, stream,
                       B1, wt(13), bh, out_w2, out_b2, (float*)d_out, NP);
}

// Round 7
// 410.457 us; speedup vs baseline: 8.1379x; 1.1189x over previous
//
#include <hip/hip_runtime.h>
#include <math.h>

// ---------------------------------------------------------------------------
// Round 7: CSR build via bucketed counting sort (kills scatter2's 18x write
// amplification).
//   binA   : per-(block,bucket) histograms (LDS), both directions, 1 edge read
//   binScan: bucket bases BB + per-(bucket,block) bases PBB (1 block)
//   binB   : packed records (val | key_local<<17) written in contiguous
//            per-(block,bucket) runs -> L2-resident lines, amp ~1
//   binC   : per-bucket: LDS node-hist + scan -> off/cnt (ordered CSR, also
//            replaces hist2/offsets), then scatter into 12-25KB local region
// GEMM pipeline + gather unchanged from round 6.
// ---------------------------------------------------------------------------

typedef unsigned short u16;
typedef __attribute__((ext_vector_type(8))) short s8v;   // 8 bf16 = 4 VGPR
typedef __attribute__((ext_vector_type(4))) float f4v;   // MFMA C/D frag

__device__ __forceinline__ float bf2f(u16 u) {
    unsigned x = ((unsigned)u) << 16;
    return __builtin_bit_cast(float, x);
}
__device__ __forceinline__ u16 f2bf(float f) {
    unsigned x = __builtin_bit_cast(unsigned, f);
    unsigned r = x + 0x7fffu + ((x >> 16) & 1u);
    return (u16)(r >> 16);
}
__device__ __forceinline__ void unpack8(uint4 u, float* f) {
    f[0] = bf2f((u16)(u.x & 0xffff)); f[1] = bf2f((u16)(u.x >> 16));
    f[2] = bf2f((u16)(u.y & 0xffff)); f[3] = bf2f((u16)(u.y >> 16));
    f[4] = bf2f((u16)(u.z & 0xffff)); f[5] = bf2f((u16)(u.z >> 16));
    f[6] = bf2f((u16)(u.w & 0xffff)); f[7] = bf2f((u16)(u.w >> 16));
}

// ---- small fp32 128x128 matmuls for folded weights ----
struct SmEnt { const float* A; const float* B; const float* s; };
struct SmPack { SmEnt e[4]; };

__global__ __launch_bounds__(256) void smallmm(SmPack p, float* __restrict__ out)
{
    int t = blockIdx.x * 256 + threadIdx.x;
    int m = t >> 14;            // 16384 outputs per product
    int o = t & 16383;
    int i = o >> 7, j = o & 127;
    SmEnt en = p.e[m];
    float acc = 0.f;
#pragma unroll 4
    for (int k = 0; k < 128; ++k) acc += en.A[i * 128 + k] * en.B[k * 128 + j];
    if (en.s) acc *= *en.s;
    out[(size_t)m * 16384 + o] = acc;
}

// folded bias vectors: [0]=sp_vc*(vc_bf@vc_wo1t), [1]=sp_cv*(cv_bf@cv_wo1t),
//                      [2]=vc_bo2@cv_wr, [3]=cv_bo2@out_w1+out_b1
__global__ void vecpre(
    const float* vc_bf, const float* vc_wo1, const float* vc_sp,
    const float* cv_bf, const float* cv_wo1, const float* cv_sp,
    const float* vc_bo2, const float* cv_wr,
    const float* cv_bo2, const float* out_w1, const float* out_b1,
    float* __restrict__ vout)
{
    int j = threadIdx.x;
    if (j >= 128) return;
    float a0 = 0.f, a1 = 0.f, a2 = 0.f, a3 = 0.f;
    for (int k = 0; k < 128; ++k) {
        a0 += vc_bf[k] * vc_wo1[k * 128 + j];
        a1 += cv_bf[k] * cv_wo1[k * 128 + j];
        a2 += vc_bo2[k] * cv_wr[k * 128 + j];
        a3 += cv_bo2[k] * out_w1[k * 128 + j];
    }
    vout[j] = a0 * (*vc_sp);
    vout[128 + j] = a1 * (*cv_sp);
    vout[256 + j] = a2;
    vout[384 + j] = a3 + out_b1[j];
}

// ---- weight conversion: fp32 [Ksrc][128] -> bf16 WT[col*Kdst + k], pad k ----
struct WEnt { const float* src; int Ksrc; int Kdst; };
struct WPack { WEnt e[14]; };

__global__ __launch_bounds__(256) void wconvert(WPack p, u16* __restrict__ wt)
{
    int t = blockIdx.x * 256 + threadIdx.x;
    int m = t >> 15;            // 32768 slots per matrix
    int i = t & 32767;
    WEnt en = p.e[m];
    if (i >= (en.Kdst << 7)) return;
    int k = i >> 7, col = i & 127;
    float v = (k < en.Ksrc) ? en.src[k * 128 + col] : 0.f;
    wt[(size_t)m * 32768 + (size_t)col * en.Kdst + k] = f2bf(v);
}

// ---- feature conversion: fp32 [M,F] -> bf16 [M,96] with prenorm ----
__global__ __launch_bounds__(256) void featconv(
    const float* __restrict__ x, const float* __restrict__ shift,
    const float* __restrict__ scale, u16* __restrict__ y,
    long total, int F)
{
    for (long i = (long)blockIdx.x * 256 + threadIdx.x; i < total;
         i += (long)gridDim.x * 256) {
        int c = (int)(i % 96);
        long r = i / 96;
        float v = 0.f;
        if (c < F) {
            v = x[r * F + c];
            v = (v + shift[c]) * scale[c];
        }
        y[i] = f2bf(v);
    }
}

// ---- register-persistent-B GEMM ----
template <int KS1, bool HASA2, bool RELU, bool GATE>
__global__ __launch_bounds__(256) void gemm_rb(
    const u16* __restrict__ A1, const u16* __restrict__ A2,
    const u16* __restrict__ WT1,     // bf16 [128][KS1*32]
    const u16* __restrict__ WT2,     // bf16 [128][128] (when HASA2)
    const float* __restrict__ bias0, // fp32 [128] or null
    const float* __restrict__ bias1, // fp32 [128] or null (gated)
    const float* __restrict__ gate,  // fp32 [M] (cnt) when GATE
    u16* __restrict__ out, int M)    // M % 16 == 0
{
    constexpr int K1 = KS1 * 32;
    constexpr bool PF = !HASA2;
    constexpr int AS = KS1 + (HASA2 ? 4 : 0);
    const int lane = threadIdx.x & 63;
    const int c = lane & 15;
    const int kg = lane >> 4;
    const int wid = blockIdx.x * 4 + (threadIdx.x >> 6);
    const int ws = gridDim.x * 4;
    const int items = M >> 4;

    const u16* wbase = WT1 + (size_t)c * K1 + kg * 8;
    s8v bp[KS1][8];
#pragma unroll
    for (int ks = 0; ks < KS1; ++ks)
#pragma unroll
        for (int nt = 0; nt < 8; ++nt)
            bp[ks][nt] = *(const s8v*)(wbase + ((size_t)nt * 16) * K1 + ks * 32);

    const u16* wbase2 = HASA2 ? (WT2 + (size_t)c * 128 + kg * 8) : nullptr;

    float bc0[8], bc1[8];
#pragma unroll
    for (int nt = 0; nt < 8; ++nt) {
        bc0[nt] = bias0 ? bias0[nt * 16 + c] : 0.f;
        bc1[nt] = (GATE && bias1) ? bias1[nt * 16 + c] : 0.f;
    }

    auto lda = [&](s8v* a, int item) {
        const u16* ap = A1 + (size_t)((item << 4) + c) * K1 + kg * 8;
#pragma unroll
        for (int ks = 0; ks < KS1; ++ks) a[ks] = *(const s8v*)(ap + ks * 32);
        if (HASA2) {
            const u16* ap2 = A2 + (size_t)((item << 4) + c) * 128 + kg * 8;
#pragma unroll
            for (int ks = 0; ks < 4; ++ks) a[KS1 + ks] = *(const s8v*)(ap2 + ks * 32);
        }
    };

    s8v a[AS], an[AS], a2[AS];
    int item = wid;
    if (item < items) lda(a, item);
    if (PF && item + ws < items) lda(an, item + ws);
    while (item < items) {
        const int i2 = item + 2 * ws;
        if (PF && i2 < items) lda(a2, i2);

        f4v acc[8];
#pragma unroll
        for (int nt = 0; nt < 8; ++nt) acc[nt] = (f4v){0.f, 0.f, 0.f, 0.f};
#pragma unroll
        for (int ks = 0; ks < KS1; ++ks)
#pragma unroll
            for (int nt = 0; nt < 8; ++nt)
                acc[nt] = __builtin_amdgcn_mfma_f32_16x16x32_bf16(a[ks], bp[ks][nt], acc[nt], 0, 0, 0);
        if (HASA2) {
#pragma unroll
            for (int ks = 0; ks < 4; ++ks)
#pragma unroll
                for (int nt = 0; nt < 8; ++nt) {
                    s8v b = *(const s8v*)(wbase2 + ((size_t)nt * 16) * 128 + ks * 32);
                    acc[nt] = __builtin_amdgcn_mfma_f32_16x16x32_bf16(a[KS1 + ks], b, acc[nt], 0, 0, 0);
                }
        }

        const int r0 = item << 4;
        float g4[4];
#pragma unroll
        for (int j = 0; j < 4; ++j)
            g4[j] = GATE ? (gate[r0 + kg * 4 + j] > 0.f ? 1.f : 0.f) : 0.f;
#pragma unroll
        for (int nt = 0; nt < 8; ++nt)
#pragma unroll
            for (int j = 0; j < 4; ++j) {
                float v = acc[nt][j] + bc0[nt] + g4[j] * bc1[nt];
                if (RELU) v = fmaxf(v, 0.f);
                out[(size_t)(r0 + kg * 4 + j) * 128 + nt * 16 + c] = f2bf(v);
            }

        if (PF) {
#pragma unroll
            for (int ks = 0; ks < AS; ++ks) { a[ks] = an[ks]; an[ks] = a2[ks]; }
        } else if (item + ws < items) {
            lda(a, item + ws);
        }
        item += ws;
    }
}

// ---- fused head: sigmoid(relu(A@W1+b1) @ w2 + b2) -> [M,2] fp32 ----
__global__ __launch_bounds__(256) void head_fused(
    const u16* __restrict__ A1, const u16* __restrict__ WT,
    const float* __restrict__ b1, const float* __restrict__ w2,
    const float* __restrict__ b2, float* __restrict__ outp, int M)
{
    constexpr int KT = 128;
    const int lane = threadIdx.x & 63;
    const int c = lane & 15;
    const int kg = lane >> 4;
    const int wid = blockIdx.x * 4 + (threadIdx.x >> 6);
    const int ws = gridDim.x * 4;
    const int items = M >> 4;

    const u16* wbase = WT + (size_t)c * KT + kg * 8;
    s8v bp[4][8];
#pragma unroll
    for (int ks = 0; ks < 4; ++ks)
#pragma unroll
        for (int nt = 0; nt < 8; ++nt)
            bp[ks][nt] = *(const s8v*)(wbase + ((size_t)nt * 16) * KT + ks * 32);

    float bc[8], w2c0[8], w2c1[8];
#pragma unroll
    for (int nt = 0; nt < 8; ++nt) {
        int col = nt * 16 + c;
        bc[nt] = b1[col];
        w2c0[nt] = w2[col * 2 + 0];
        w2c1[nt] = w2[col * 2 + 1];
    }
    const float s0 = b2[0], s1 = b2[1];

    for (int item = wid; item < items; item += ws) {
        const int r0 = item << 4;
        const u16* ap = A1 + (size_t)(r0 + c) * 128 + kg * 8;
        s8v a[4];
#pragma unroll
        for (int ks = 0; ks < 4; ++ks) a[ks] = *(const s8v*)(ap + ks * 32);

        f4v acc[8];
#pragma unroll
        for (int nt = 0; nt < 8; ++nt) acc[nt] = (f4v){0.f, 0.f, 0.f, 0.f};
#pragma unroll
        for (int ks = 0; ks < 4; ++ks)
#pragma unroll
            for (int nt = 0; nt < 8; ++nt)
                acc[nt] = __builtin_amdgcn_mfma_f32_16x16x32_bf16(a[ks], bp[ks][nt], acc[nt], 0, 0, 0);

        float pp0[4] = {0.f, 0.f, 0.f, 0.f}, pp1[4] = {0.f, 0.f, 0.f, 0.f};
#pragma unroll
        for (int nt = 0; nt < 8; ++nt)
#pragma unroll
            for (int j = 0; j < 4; ++j) {
                float v = fmaxf(acc[nt][j] + bc[nt], 0.f);
                pp0[j] += v * w2c0[nt];
                pp1[j] += v * w2c1[nt];
            }
#pragma unroll
        for (int m = 1; m < 16; m <<= 1)
#pragma unroll
            for (int j = 0; j < 4; ++j) {
                pp0[j] += __shfl_xor(pp0[j], m);
                pp1[j] += __shfl_xor(pp1[j], m);
            }
        if (c == 0) {
#pragma unroll
            for (int j = 0; j < 4; ++j) {
                int row = r0 + kg * 4 + j;
                outp[(size_t)row * 2 + 0] = 1.f / (1.f + expf(-(pp0[j] + s0)));
                outp[(size_t)row * 2 + 1] = 1.f / (1.f + expf(-(pp1[j] + s1)));
            }
        }
    }
}

// ============================ CSR counting sort ============================
// bucket = key >> 9 (512 nodes). Children buckets [0,nbk_c), pivot buckets
// [nbk_c, NBK). Records: val | (key&511)<<17 (val < 2^17).

__global__ __launch_bounds__(256) void binA(
    const int* __restrict__ src, const int* __restrict__ dst,
    int E, int CH, int NB, int nbk_c, int NBK, int* __restrict__ G)
{
    __shared__ int h[1024];
    const int blk = blockIdx.x, tid = threadIdx.x;
    for (int i = tid; i < NBK; i += 256) h[i] = 0;
    __syncthreads();
    const int e0 = blk * CH, e1 = min(E, e0 + CH);
    for (int e = e0 + tid; e < e1; e += 256) {
        atomicAdd(&h[dst[e] >> 9], 1);
        atomicAdd(&h[nbk_c + (src[e] >> 9)], 1);
    }
    __syncthreads();
    for (int b = tid; b < NBK; b += 256) G[b * NB + blk] = h[b];
}

__global__ __launch_bounds__(512) void binScan(
    const int* __restrict__ G, int NB, int NBK,
    int* __restrict__ BB, int* __restrict__ PBB)
{
    __shared__ int wsum[8];
    const int tid = threadIdx.x;
    int T = 0;
    if (tid < NBK) {
        const int* g = G + (size_t)tid * NB;
        for (int i = 0; i < NB; ++i) T += g[i];
    }
    const int lane = tid & 63, wv = tid >> 6;
    int incl = T;
#pragma unroll
    for (int d = 1; d < 64; d <<= 1) {
        int up = __shfl_up(incl, d);
        if (lane >= d) incl += up;
    }
    if (lane == 63) wsum[wv] = incl;
    __syncthreads();
    if (tid == 0) {
        int run = 0;
        for (int w = 0; w < 8; ++w) { int t = wsum[w]; wsum[w] = run; run += t; }
    }
    __syncthreads();
    const int base = wsum[wv] + incl - T;   // exclusive prefix
    if (tid < NBK) {
        BB[tid] = base;
        if (tid == NBK - 1) BB[NBK] = base + T;
        int run = base;
        int* p = PBB + (size_t)tid * NB;
        const int* g = G + (size_t)tid * NB;
        for (int i = 0; i < NB; ++i) { p[i] = run; run += g[i]; }
    }
}

__global__ __launch_bounds__(256) void binB(
    const int* __restrict__ src, const int* __restrict__ dst,
    int E, int CH, int NB, int nbk_c, int NBK,
    const int* __restrict__ PBB, unsigned* __restrict__ REC)
{
    __shared__ int fill[1024];
    const int blk = blockIdx.x, tid = threadIdx.x;
    for (int i = tid; i < NBK; i += 256) fill[i] = 0;
    __syncthreads();
    const int e0 = blk * CH, e1 = min(E, e0 + CH);
    for (int e = e0 + tid; e < e1; e += 256) {
        const int s = src[e], d = dst[e];
        const int bc = d >> 9;
        const int pc = PBB[bc * NB + blk] + atomicAdd(&fill[bc], 1);
        REC[pc] = (unsigned)s | ((unsigned)(d & 511) << 17);
        const int bp = nbk_c + (s >> 9);
        const int pp = PBB[bp * NB + blk] + atomicAdd(&fill[bp], 1);
        REC[pp] = (unsigned)d | ((unsigned)(s & 511) << 17);
    }
}

__global__ __launch_bounds__(256) void binC(
    const unsigned* __restrict__ REC, const int* __restrict__ BB,
    int bucket_base, int Nn,
    int* __restrict__ off_out, int* __restrict__ cnt_out, int* __restrict__ AJ)
{
    __shared__ int nh[512], lo[512], fl[512], ws2[4];
    const int b = blockIdx.x, tid = threadIdx.x;
    const int gb = bucket_base + b;
    const int r0 = BB[gb], r1 = BB[gb + 1];
    const int node0 = b << 9;
    const int kmax = min(512, Nn - node0);
    nh[tid] = 0; nh[tid + 256] = 0;
    fl[tid] = 0; fl[tid + 256] = 0;
    __syncthreads();
    for (int i = r0 + tid; i < r1; i += 256)
        atomicAdd(&nh[REC[i] >> 17], 1);
    __syncthreads();
    // exclusive scan nh[512] -> lo[512]
    const int v0 = nh[2 * tid], v1 = nh[2 * tid + 1];
    const int s = v0 + v1;
    const int lane = tid & 63, wv = tid >> 6;
    int incl = s;
#pragma unroll
    for (int d = 1; d < 64; d <<= 1) {
        int up = __shfl_up(incl, d);
        if (lane >= d) incl += up;
    }
    if (lane == 63) ws2[wv] = incl;
    __syncthreads();
    if (tid == 0) {
        int run = 0;
        for (int w = 0; w < 4; ++w) { int t = ws2[w]; ws2[w] = run; run += t; }
    }
    __syncthreads();
    const int base = ws2[wv] + incl - s;
    lo[2 * tid] = base;
    lo[2 * tid + 1] = base + v0;
    __syncthreads();
    for (int k = tid; k < kmax; k += 256) {
        off_out[node0 + k] = r0 + lo[k];
        cnt_out[node0 + k] = nh[k];
    }
    for (int i = r0 + tid; i < r1; i += 256) {
        const unsigned rec = REC[i];
        const int k = rec >> 17;
        const int pos = r0 + lo[k] + atomicAdd(&fl[k], 1);
        AJ[pos] = (int)(rec & 0x1FFFFu);
    }
}

// ---- gather: Sdiv[n] = mean_e relu((RW[n]+LW[adj])*sf) ----
__global__ __launch_bounds__(256) void node_gather2(
    const int* __restrict__ off, const int* __restrict__ cnt,
    const int* __restrict__ adj,
    const u16* __restrict__ RW, const u16* __restrict__ LW,
    u16* __restrict__ Sdiv, float* __restrict__ cntf,
    const float* __restrict__ sf_p, int N)
{
    int t = blockIdx.x * 256 + threadIdx.x;
    int n = t >> 5;
    if (n >= N) return;
    int l32 = t & 31;
    int c = l32 & 15;          // 16B chunk (8 bf16) within the row
    int half = l32 >> 4;       // 0/1: edge parity
    const float sf = *sf_p;
    const int start = off[n], len = cnt[n];

    float rw[8];
    unpack8(*(const uint4*)(RW + (size_t)n * 128 + c * 8), rw);
    float acc[8] = {0.f, 0.f, 0.f, 0.f, 0.f, 0.f, 0.f, 0.f};

    for (int i = half; i < len; i += 2) {
        int l = adj[start + i];
        float lw[8];
        unpack8(*(const uint4*)(LW + (size_t)l * 128 + c * 8), lw);
#pragma unroll
        for (int j = 0; j < 8; ++j)
            acc[j] += fmaxf((rw[j] + lw[j]) * sf, 0.f);
    }
#pragma unroll
    for (int j = 0; j < 8; ++j) acc[j] += __shfl_xor(acc[j], 16);

    if (half == 0) {
        float inv = 1.f / fmaxf((float)len, 1.f);
        uint4 o;
        o.x = (unsigned)f2bf(acc[0] * inv) | ((unsigned)f2bf(acc[1] * inv) << 16);
        o.y = (unsigned)f2bf(acc[2] * inv) | ((unsigned)f2bf(acc[3] * inv) << 16);
        o.z = (unsigned)f2bf(acc[4] * inv) | ((unsigned)f2bf(acc[5] * inv) << 16);
        o.w = (unsigned)f2bf(acc[6] * inv) | ((unsigned)f2bf(acc[7] * inv) << 16);
        *(uint4*)(Sdiv + (size_t)n * 128 + c * 8) = o;
        if (l32 == 0) cntf[n] = (float)len;
    }
}

extern "C" void kernel_launch(void* const* d_in, const int* in_sizes, int n_in,
                              void* d_out, int out_size, void* d_ws, size_t ws_size,
                              hipStream_t stream)
{
    const float* pivot = (const float*)d_in[0];
    const float* child = (const float*)d_in[1];
    const int* edges = (const int*)d_in[2];
    const int F = in_sizes[3];           // 69
    const int NP = in_sizes[0] / F;
    const int NC = in_sizes[1] / F;
    const int E = in_sizes[2] / 2;
    const int* src = edges;
    const int* dst = edges + E;

    const float *pe_shift = (const float*)d_in[3], *pe_scale = (const float*)d_in[4],
                *pe_w1 = (const float*)d_in[5], *pe_b1 = (const float*)d_in[6],
                *pe_w2 = (const float*)d_in[7], *pe_b2 = (const float*)d_in[8];
    const float *ce_shift = (const float*)d_in[9], *ce_scale = (const float*)d_in[10],
                *ce_w1 = (const float*)d_in[11], *ce_b1 = (const float*)d_in[12],
                *ce_w2 = (const float*)d_in[13], *ce_b2 = (const float*)d_in[14];
    const float *vc_wl = (const float*)d_in[15], *vc_bl = (const float*)d_in[16],
                *vc_wr = (const float*)d_in[17], *vc_sf = (const float*)d_in[18],
                *vc_wf = (const float*)d_in[19], *vc_bf = (const float*)d_in[20],
                *vc_sp = (const float*)d_in[21], *vc_wo1 = (const float*)d_in[22],
                *vc_bo1 = (const float*)d_in[23], *vc_wo2 = (const float*)d_in[24],
                *vc_bo2 = (const float*)d_in[25];
    const float *cv_wl = (const float*)d_in[26], *cv_bl = (const float*)d_in[27],
                *cv_wr = (const float*)d_in[28], *cv_sf = (const float*)d_in[29],
                *cv_wf = (const float*)d_in[30], *cv_bf = (const float*)d_in[31],
                *cv_sp = (const float*)d_in[32], *cv_wo1 = (const float*)d_in[33],
                *cv_bo1 = (const float*)d_in[34], *cv_wo2 = (const float*)d_in[35],
                *cv_bo2 = (const float*)d_in[36];
    const float *out_w1 = (const float*)d_in[37], *out_b1 = (const float*)d_in[38],
                *out_w2 = (const float*)d_in[39], *out_b2 = (const float*)d_in[40];

    // ---- workspace carve (256B aligned) ----
    char* base = (char*)d_ws;
    size_t off = 0;
    auto carve = [&](size_t bytes) {
        void* p = base + off;
        off += (bytes + 255) & ~(size_t)255;
        return p;
    };
    float* Wsc = (float*)carve((size_t)4 * 16384 * 4);   // folded fp32 products
    float* Vsc = (float*)carve((size_t)4 * 128 * 4);     // folded bias vectors
    u16* WT = (u16*)carve((size_t)14 * 32768 * 2);
    u16* FP = (u16*)carve((size_t)NP * 96 * 2);
    u16* FC = (u16*)carve((size_t)NC * 96 * 2);
    u16* B0 = (u16*)carve((size_t)NP * 128 * 2);   // pv0
    u16* B1 = (u16*)carve((size_t)NC * 128 * 2);
    u16* B2 = (u16*)carve((size_t)NC * 128 * 2);
    u16* B3 = (u16*)carve((size_t)NC * 128 * 2);
    u16* B4 = (u16*)carve((size_t)NC * 128 * 2);
    const int NMAX = (NC > NP) ? NC : NP;
    float* cntf = (float*)carve((size_t)NMAX * 4);

    // counting-sort workspace
    const int NB = 120;                       // binning blocks
    const int CH = (E + NB - 1) / NB;         // edges per block chunk
    const int nbk_c = (NC + 511) >> 9;
    const int nbk_p = (NP + 511) >> 9;
    const int NBK = nbk_c + nbk_p;            // <= 1024
    int* cnt_c = (int*)carve((size_t)NC * 4);
    int* cnt_p = (int*)carve((size_t)NP * 4);
    int* off_c = (int*)carve((size_t)NC * 4);
    int* off_p = (int*)carve((size_t)NP * 4);
    int* G = (int*)carve((size_t)NBK * NB * 4);
    int* PBB = (int*)carve((size_t)NBK * NB * 4);
    int* BB = (int*)carve((size_t)(NBK + 1) * 4);
    unsigned* REC = (unsigned*)carve((size_t)2 * E * 4);
    int* AJ = (int*)carve((size_t)2 * E * 4);

    // ---- folded weight precompute (fp32) ----
    SmPack sp;
    sp.e[0] = {vc_wf, vc_wo1, vc_sp};            // Wfo_vc = sp*(wf@wo1t)
    sp.e[1] = {cv_wf, cv_wo1, cv_sp};            // Wfo_cv
    sp.e[2] = {vc_wo2, cv_wr, nullptr};          // Wx = vc_wo2@cv_wr
    sp.e[3] = {cv_wo2, out_w1, nullptr};         // Wh = cv_wo2@out_w1
    hipLaunchKernelGGL(smallmm, dim3(256), dim3(256), 0, stream, sp, Wsc);
    hipLaunchKernelGGL(vecpre, dim3(1), dim3(128), 0, stream,
                       vc_bf, vc_wo1, vc_sp, cv_bf, cv_wo1, cv_sp,
                       vc_bo2, cv_wr, cv_bo2, out_w1, out_b1, Vsc);
    const float* cvec_vc = Vsc;
    const float* cvec_cv = Vsc + 128;
    const float* cx = Vsc + 256;
    const float* bh = Vsc + 384;

    // ---- weight conversion ----
    WPack wp;
    auto setw = [&](int i, const float* s, int ks, int kd) {
        wp.e[i].src = s; wp.e[i].Ksrc = ks; wp.e[i].Kdst = kd;
    };
    setw(0, pe_w1, F, 96);            setw(1, pe_w2, 128, 128);
    setw(2, ce_w1, F, 96);            setw(3, ce_w2, 128, 128);
    setw(4, vc_wl, 128, 128);         setw(5, vc_wr, 128, 128);
    setw(6, Wsc + 0 * 16384, 128, 128);       // Wfo_vc
    setw(7, vc_wo1 + 128 * 128, 128, 128);    // vc wo1 bottom (ch0 part)
    setw(8, Wsc + 2 * 16384, 128, 128);       // Wx
    setw(9, cv_wl, 128, 128);         setw(10, cv_wr, 128, 128);
    setw(11, Wsc + 1 * 16384, 128, 128);      // Wfo_cv
    setw(12, cv_wo1 + 128 * 128, 128, 128);   // cv wo1 bottom (pv0 part)
    setw(13, Wsc + 3 * 16384, 128, 128);      // Wh
    hipLaunchKernelGGL(wconvert, dim3(14 * 128), dim3(256), 0, stream, wp, WT);
    auto wt = [&](int i) { return WT + (size_t)i * 32768; };

    // ---- feature conversion ----
    hipLaunchKernelGGL(featconv, dim3(2048), dim3(256), 0, stream,
                       pivot, pe_shift, pe_scale, FP, (long)NP * 96, F);
    hipLaunchKernelGGL(featconv, dim3(2048), dim3(256), 0, stream,
                       child, ce_shift, ce_scale, FC, (long)NC * 96, F);

    // ---- CSR via counting sort ----
    hipLaunchKernelGGL(binA, dim3(NB), dim3(256), 0, stream,
                       src, dst, E, CH, NB, nbk_c, NBK, G);
    hipLaunchKernelGGL(binScan, dim3(1), dim3(512), 0, stream,
                       G, NB, NBK, BB, PBB);
    hipLaunchKernelGGL(binB, dim3(NB), dim3(256), 0, stream,
                       src, dst, E, CH, NB, nbk_c, NBK, PBB, REC);
    hipLaunchKernelGGL(binC, dim3(nbk_c), dim3(256), 0, stream,
                       REC, BB, 0, NC, off_c, cnt_c, AJ);
    hipLaunchKernelGGL(binC, dim3(nbk_p), dim3(256), 0, stream,
                       REC, BB, nbk_c, NP, off_p, cnt_p, AJ);

    // ---- GEMM pipeline ----
    const dim3 blk(256);
    auto grd = [](int M) {
        int items = M >> 4;
        int b = (items + 3) / 4;
        return dim3((unsigned)(b < 512 ? b : 512));
    };

    // embeddings
    gemm_rb<3, false, true, false><<<grd(NP), blk, 0, stream>>>(
        FP, nullptr, wt(0), nullptr, pe_b1, nullptr, nullptr, B1, NP);
    gemm_rb<4, false, true, false><<<grd(NP), blk, 0, stream>>>(
        B1, nullptr, wt(1), nullptr, pe_b2, nullptr, nullptr, B0, NP);   // pv0
    gemm_rb<3, false, true, false><<<grd(NC), blk, 0, stream>>>(
        FC, nullptr, wt(2), nullptr, ce_b1, nullptr, nullptr, B1, NC);
    gemm_rb<4, false, true, false><<<grd(NC), blk, 0, stream>>>(
        B1, nullptr, wt(3), nullptr, ce_b2, nullptr, nullptr, B2, NC);   // ch0

    // conv v->c (aggregate to children)
    gemm_rb<4, false, false, false><<<grd(NC), blk, 0, stream>>>(
        B2, nullptr, wt(4), nullptr, vc_bl, nullptr, nullptr, B1, NC);   // RW_c
    gemm_rb<4, false, false, false><<<grd(NP), blk, 0, stream>>>(
        B0, nullptr, wt(5), nullptr, nullptr, nullptr, nullptr, B3, NP); // LW_v
    hipLaunchKernelGGL(node_gather2, dim3(((size_t)NC * 32 + 255) / 256), blk, 0,
                       stream, off_c, cnt_c, AJ, B1, B3, B4, cntf, vc_sf, NC);
    // h_c = relu(Sdiv@Wfo_vc + ch0@wo1b + bo1 + gate*cvec)
    gemm_rb<4, true, true, true><<<grd(NC), blk, 0, stream>>>(
        B4, B2, wt(6), wt(7), vc_bo1, cvec_vc, cntf, B1, NC);            // h_c
    gemm_rb<4, false, false, false><<<grd(NC), blk, 0, stream>>>(
        B1, nullptr, wt(8), nullptr, cx, nullptr, nullptr, B3, NC);      // LW_c

    // conv c->v (aggregate to pivot)
    gemm_rb<4, false, false, false><<<grd(NP), blk, 0, stream>>>(
        B0, nullptr, wt(9), nullptr, cv_bl, nullptr, nullptr, B2, NP);   // RW_p
    hipLaunchKernelGGL(node_gather2, dim3(((size_t)NP * 32 + 255) / 256), blk, 0,
                       stream, off_p, cnt_p, AJ, B2, B3, B4, cntf, cv_sf, NP);
    // h_p = relu(Sdiv@Wfo_cv + pv0@wo1b + bo1 + gate*cvec)
    gemm_rb<4, true, true, true><<<grd(NP), blk, 0, stream>>>(
        B4, B0, wt(11), wt(12), cv_bo1, cvec_cv, cntf, B1, NP);          // h_p

    // fused head on h_p with folded W1'=Wh, b1'=bh
    hipLaunchKernelGGL(head_fused, grd(NP), blk, 0, stream,
                       B1, wt(13), bh, out_w2, out_b2, (float*)d_out, NP);
}

// Round 8
// 362.000 us; speedup vs baseline: 9.2272x; 1.1339x over previous
//
#include <hip/hip_runtime.h>
#include <math.h>

// ---------------------------------------------------------------------------
// Round 8: parallelize the CSR scan stage (round 7's binScan was a 58us
// single-block serial kernel).
//   binA : per-(block,bucket) histograms -> G, plus bucket totals Tb (atomic)
//   binS : 1-block shuffle scan over NBK bucket totals -> BB (no serial loops)
//   binP : one wave per bucket scans its G row (+BB[b]) -> PBB
//   binB/binC unchanged. GEMM pipeline + gather unchanged from round 7.
// ---------------------------------------------------------------------------

typedef unsigned short u16;
typedef __attribute__((ext_vector_type(8))) short s8v;   // 8 bf16 = 4 VGPR
typedef __attribute__((ext_vector_type(4))) float f4v;   // MFMA C/D frag

__device__ __forceinline__ float bf2f(u16 u) {
    unsigned x = ((unsigned)u) << 16;
    return __builtin_bit_cast(float, x);
}
__device__ __forceinline__ u16 f2bf(float f) {
    unsigned x = __builtin_bit_cast(unsigned, f);
    unsigned r = x + 0x7fffu + ((x >> 16) & 1u);
    return (u16)(r >> 16);
}
__device__ __forceinline__ void unpack8(uint4 u, float* f) {
    f[0] = bf2f((u16)(u.x & 0xffff)); f[1] = bf2f((u16)(u.x >> 16));
    f[2] = bf2f((u16)(u.y & 0xffff)); f[3] = bf2f((u16)(u.y >> 16));
    f[4] = bf2f((u16)(u.z & 0xffff)); f[5] = bf2f((u16)(u.z >> 16));
    f[6] = bf2f((u16)(u.w & 0xffff)); f[7] = bf2f((u16)(u.w >> 16));
}

// ---- small fp32 128x128 matmuls for folded weights ----
struct SmEnt { const float* A; const float* B; const float* s; };
struct SmPack { SmEnt e[4]; };

__global__ __launch_bounds__(256) void smallmm(SmPack p, float* __restrict__ out)
{
    int t = blockIdx.x * 256 + threadIdx.x;
    int m = t >> 14;            // 16384 outputs per product
    int o = t & 16383;
    int i = o >> 7, j = o & 127;
    SmEnt en = p.e[m];
    float acc = 0.f;
#pragma unroll 4
    for (int k = 0; k < 128; ++k) acc += en.A[i * 128 + k] * en.B[k * 128 + j];
    if (en.s) acc *= *en.s;
    out[(size_t)m * 16384 + o] = acc;
}

// folded bias vectors: [0]=sp_vc*(vc_bf@vc_wo1t), [1]=sp_cv*(cv_bf@cv_wo1t),
//                      [2]=vc_bo2@cv_wr, [3]=cv_bo2@out_w1+out_b1
__global__ void vecpre(
    const float* vc_bf, const float* vc_wo1, const float* vc_sp,
    const float* cv_bf, const float* cv_wo1, const float* cv_sp,
    const float* vc_bo2, const float* cv_wr,
    const float* cv_bo2, const float* out_w1, const float* out_b1,
    float* __restrict__ vout)
{
    int j = threadIdx.x;
    if (j >= 128) return;
    float a0 = 0.f, a1 = 0.f, a2 = 0.f, a3 = 0.f;
    for (int k = 0; k < 128; ++k) {
        a0 += vc_bf[k] * vc_wo1[k * 128 + j];
        a1 += cv_bf[k] * cv_wo1[k * 128 + j];
        a2 += vc_bo2[k] * cv_wr[k * 128 + j];
        a3 += cv_bo2[k] * out_w1[k * 128 + j];
    }
    vout[j] = a0 * (*vc_sp);
    vout[128 + j] = a1 * (*cv_sp);
    vout[256 + j] = a2;
    vout[384 + j] = a3 + out_b1[j];
}

// ---- weight conversion: fp32 [Ksrc][128] -> bf16 WT[col*Kdst + k], pad k ----
struct WEnt { const float* src; int Ksrc; int Kdst; };
struct WPack { WEnt e[14]; };

__global__ __launch_bounds__(256) void wconvert(WPack p, u16* __restrict__ wt)
{
    int t = blockIdx.x * 256 + threadIdx.x;
    int m = t >> 15;            // 32768 slots per matrix
    int i = t & 32767;
    WEnt en = p.e[m];
    if (i >= (en.Kdst << 7)) return;
    int k = i >> 7, col = i & 127;
    float v = (k < en.Ksrc) ? en.src[k * 128 + col] : 0.f;
    wt[(size_t)m * 32768 + (size_t)col * en.Kdst + k] = f2bf(v);
}

// ---- feature conversion: fp32 [M,F] -> bf16 [M,96] with prenorm ----
__global__ __launch_bounds__(256) void featconv(
    const float* __restrict__ x, const float* __restrict__ shift,
    const float* __restrict__ scale, u16* __restrict__ y,
    long total, int F)
{
    for (long i = (long)blockIdx.x * 256 + threadIdx.x; i < total;
         i += (long)gridDim.x * 256) {
        int c = (int)(i % 96);
        long r = i / 96;
        float v = 0.f;
        if (c < F) {
            v = x[r * F + c];
            v = (v + shift[c]) * scale[c];
        }
        y[i] = f2bf(v);
    }
}

// ---- register-persistent-B GEMM ----
template <int KS1, bool HASA2, bool RELU, bool GATE>
__global__ __launch_bounds__(256) void gemm_rb(
    const u16* __restrict__ A1, const u16* __restrict__ A2,
    const u16* __restrict__ WT1,     // bf16 [128][KS1*32]
    const u16* __restrict__ WT2,     // bf16 [128][128] (when HASA2)
    const float* __restrict__ bias0, // fp32 [128] or null
    const float* __restrict__ bias1, // fp32 [128] or null (gated)
    const float* __restrict__ gate,  // fp32 [M] (cnt) when GATE
    u16* __restrict__ out, int M)    // M % 16 == 0
{
    constexpr int K1 = KS1 * 32;
    constexpr bool PF = !HASA2;
    constexpr int AS = KS1 + (HASA2 ? 4 : 0);
    const int lane = threadIdx.x & 63;
    const int c = lane & 15;
    const int kg = lane >> 4;
    const int wid = blockIdx.x * 4 + (threadIdx.x >> 6);
    const int ws = gridDim.x * 4;
    const int items = M >> 4;

    const u16* wbase = WT1 + (size_t)c * K1 + kg * 8;
    s8v bp[KS1][8];
#pragma unroll
    for (int ks = 0; ks < KS1; ++ks)
#pragma unroll
        for (int nt = 0; nt < 8; ++nt)
            bp[ks][nt] = *(const s8v*)(wbase + ((size_t)nt * 16) * K1 + ks * 32);

    const u16* wbase2 = HASA2 ? (WT2 + (size_t)c * 128 + kg * 8) : nullptr;

    float bc0[8], bc1[8];
#pragma unroll
    for (int nt = 0; nt < 8; ++nt) {
        bc0[nt] = bias0 ? bias0[nt * 16 + c] : 0.f;
        bc1[nt] = (GATE && bias1) ? bias1[nt * 16 + c] : 0.f;
    }

    auto lda = [&](s8v* a, int item) {
        const u16* ap = A1 + (size_t)((item << 4) + c) * K1 + kg * 8;
#pragma unroll
        for (int ks = 0; ks < KS1; ++ks) a[ks] = *(const s8v*)(ap + ks * 32);
        if (HASA2) {
            const u16* ap2 = A2 + (size_t)((item << 4) + c) * 128 + kg * 8;
#pragma unroll
            for (int ks = 0; ks < 4; ++ks) a[KS1 + ks] = *(const s8v*)(ap2 + ks * 32);
        }
    };

    s8v a[AS], an[AS], a2[AS];
    int item = wid;
    if (item < items) lda(a, item);
    if (PF && item + ws < items) lda(an, item + ws);
    while (item < items) {
        const int i2 = item + 2 * ws;
        if (PF && i2 < items) lda(a2, i2);

        f4v acc[8];
#pragma unroll
        for (int nt = 0; nt < 8; ++nt) acc[nt] = (f4v){0.f, 0.f, 0.f, 0.f};
#pragma unroll
        for (int ks = 0; ks < KS1; ++ks)
#pragma unroll
            for (int nt = 0; nt < 8; ++nt)
                acc[nt] = __builtin_amdgcn_mfma_f32_16x16x32_bf16(a[ks], bp[ks][nt], acc[nt], 0, 0, 0);
        if (HASA2) {
#pragma unroll
            for (int ks = 0; ks < 4; ++ks)
#pragma unroll
                for (int nt = 0; nt < 8; ++nt) {
                    s8v b = *(const s8v*)(wbase2 + ((size_t)nt * 16) * 128 + ks * 32);
                    acc[nt] = __builtin_amdgcn_mfma_f32_16x16x32_bf16(a[KS1 + ks], b, acc[nt], 0, 0, 0);
                }
        }

        const int r0 = item << 4;
        float g4[4];
#pragma unroll
        for (int j = 0; j < 4; ++j)
            g4[j] = GATE ? (gate[r0 + kg * 4 + j] > 0.f ? 1.f : 0.f) : 0.f;
#pragma unroll
        for (int nt = 0; nt < 8; ++nt)
#pragma unroll
            for (int j = 0; j < 4; ++j) {
                float v = acc[nt][j] + bc0[nt] + g4[j] * bc1[nt];
                if (RELU) v = fmaxf(v, 0.f);
                out[(size_t)(r0 + kg * 4 + j) * 128 + nt * 16 + c] = f2bf(v);
            }

        if (PF) {
#pragma unroll
            for (int ks = 0; ks < AS; ++ks) { a[ks] = an[ks]; an[ks] = a2[ks]; }
        } else if (item + ws < items) {
            lda(a, item + ws);
        }
        item += ws;
    }
}

// ---- fused head: sigmoid(relu(A@W1+b1) @ w2 + b2) -> [M,2] fp32 ----
__global__ __launch_bounds__(256) void head_fused(
    const u16* __restrict__ A1, const u16* __restrict__ WT,
    const float* __restrict__ b1, const float* __restrict__ w2,
    const float* __restrict__ b2, float* __restrict__ outp, int M)
{
    constexpr int KT = 128;
    const int lane = threadIdx.x & 63;
    const int c = lane & 15;
    const int kg = lane >> 4;
    const int wid = blockIdx.x * 4 + (threadIdx.x >> 6);
    const int ws = gridDim.x * 4;
    const int items = M >> 4;

    const u16* wbase = WT + (size_t)c * KT + kg * 8;
    s8v bp[4][8];
#pragma unroll
    for (int ks = 0; ks < 4; ++ks)
#pragma unroll
        for (int nt = 0; nt < 8; ++nt)
            bp[ks][nt] = *(const s8v*)(wbase + ((size_t)nt * 16) * KT + ks * 32);

    float bc[8], w2c0[8], w2c1[8];
#pragma unroll
    for (int nt = 0; nt < 8; ++nt) {
        int col = nt * 16 + c;
        bc[nt] = b1[col];
        w2c0[nt] = w2[col * 2 + 0];
        w2c1[nt] = w2[col * 2 + 1];
    }
    const float s0 = b2[0], s1 = b2[1];

    for (int item = wid; item < items; item += ws) {
        const int r0 = item << 4;
        const u16* ap = A1 + (size_t)(r0 + c) * 128 + kg * 8;
        s8v a[4];
#pragma unroll
        for (int ks = 0; ks < 4; ++ks) a[ks] = *(const s8v*)(ap + ks * 32);

        f4v acc[8];
#pragma unroll
        for (int nt = 0; nt < 8; ++nt) acc[nt] = (f4v){0.f, 0.f, 0.f, 0.f};
#pragma unroll
        for (int ks = 0; ks < 4; ++ks)
#pragma unroll
            for (int nt = 0; nt < 8; ++nt)
                acc[nt] = __builtin_amdgcn_mfma_f32_16x16x32_bf16(a[ks], bp[ks][nt], acc[nt], 0, 0, 0);

        float pp0[4] = {0.f, 0.f, 0.f, 0.f}, pp1[4] = {0.f, 0.f, 0.f, 0.f};
#pragma unroll
        for (int nt = 0; nt < 8; ++nt)
#pragma unroll
            for (int j = 0; j < 4; ++j) {
                float v = fmaxf(acc[nt][j] + bc[nt], 0.f);
                pp0[j] += v * w2c0[nt];
                pp1[j] += v * w2c1[nt];
            }
#pragma unroll
        for (int m = 1; m < 16; m <<= 1)
#pragma unroll
            for (int j = 0; j < 4; ++j) {
                pp0[j] += __shfl_xor(pp0[j], m);
                pp1[j] += __shfl_xor(pp1[j], m);
            }
        if (c == 0) {
#pragma unroll
            for (int j = 0; j < 4; ++j) {
                int row = r0 + kg * 4 + j;
                outp[(size_t)row * 2 + 0] = 1.f / (1.f + expf(-(pp0[j] + s0)));
                outp[(size_t)row * 2 + 1] = 1.f / (1.f + expf(-(pp1[j] + s1)));
            }
        }
    }
}

// ============================ CSR counting sort ============================
// bucket = key >> 9 (512 nodes). Children buckets [0,nbk_c), pivot buckets
// [nbk_c, NBK). Records: val | (key&511)<<17 (val < 2^17).

__global__ __launch_bounds__(256) void binA(
    const int* __restrict__ src, const int* __restrict__ dst,
    int E, int CH, int NB, int nbk_c, int NBK,
    int* __restrict__ G, int* __restrict__ Tb)
{
    __shared__ int h[1024];
    const int blk = blockIdx.x, tid = threadIdx.x;
    for (int i = tid; i < NBK; i += 256) h[i] = 0;
    __syncthreads();
    const int e0 = blk * CH, e1 = min(E, e0 + CH);
    for (int e = e0 + tid; e < e1; e += 256) {
        atomicAdd(&h[dst[e] >> 9], 1);
        atomicAdd(&h[nbk_c + (src[e] >> 9)], 1);
    }
    __syncthreads();
    for (int b = tid; b < NBK; b += 256) {
        const int v = h[b];
        G[b * NB + blk] = v;
        if (v) atomicAdd(&Tb[b], v);
    }
}

// 1-block shuffle scan over NBK bucket totals -> BB (exclusive) + BB[NBK]
__global__ __launch_bounds__(512) void binS(
    const int* __restrict__ Tb, int NBK, int* __restrict__ BB)
{
    __shared__ int wsum[8];
    const int tid = threadIdx.x;
    const int T = (tid < NBK) ? Tb[tid] : 0;
    const int lane = tid & 63, wv = tid >> 6;
    int incl = T;
#pragma unroll
    for (int d = 1; d < 64; d <<= 1) {
        int up = __shfl_up(incl, d);
        if (lane >= d) incl += up;
    }
    if (lane == 63) wsum[wv] = incl;
    __syncthreads();
    if (tid == 0) {
        int run = 0;
        for (int w = 0; w < 8; ++w) { int t = wsum[w]; wsum[w] = run; run += t; }
    }
    __syncthreads();
    const int base = wsum[wv] + incl - T;
    if (tid < NBK) {
        BB[tid] = base;
        if (tid == NBK - 1) BB[NBK] = base + T;
    }
}

// one 64-lane block per bucket: exclusive scan of G row (+BB[b]) -> PBB row
__global__ __launch_bounds__(64) void binP(
    const int* __restrict__ G, const int* __restrict__ BB,
    int NB, int* __restrict__ PBB)
{
    const int b = blockIdx.x, l = threadIdx.x;
    const int* g = G + (size_t)b * NB;
    const int v0 = (l < NB) ? g[l] : 0;
    const int v1 = (l + 64 < NB) ? g[l + 64] : 0;
    int i0 = v0, i1 = v1;
#pragma unroll
    for (int d = 1; d < 64; d <<= 1) {
        int u0 = __shfl_up(i0, d);
        int u1 = __shfl_up(i1, d);
        if (l >= d) { i0 += u0; i1 += u1; }
    }
    const int t0 = __shfl(i0, 63);
    const int base = BB[b];
    int* p = PBB + (size_t)b * NB;
    if (l < NB) p[l] = base + i0 - v0;
    if (l + 64 < NB) p[l + 64] = base + t0 + i1 - v1;
}

__global__ __launch_bounds__(256) void binB(
    const int* __restrict__ src, const int* __restrict__ dst,
    int E, int CH, int NB, int nbk_c, int NBK,
    const int* __restrict__ PBB, unsigned* __restrict__ REC)
{
    __shared__ int fill[1024];
    const int blk = blockIdx.x, tid = threadIdx.x;
    for (int i = tid; i < NBK; i += 256) fill[i] = 0;
    __syncthreads();
    const int e0 = blk * CH, e1 = min(E, e0 + CH);
    for (int e = e0 + tid; e < e1; e += 256) {
        const int s = src[e], d = dst[e];
        const int bc = d >> 9;
        const int pc = PBB[bc * NB + blk] + atomicAdd(&fill[bc], 1);
        REC[pc] = (unsigned)s | ((unsigned)(d & 511) << 17);
        const int bp = nbk_c + (s >> 9);
        const int pp = PBB[bp * NB + blk] + atomicAdd(&fill[bp], 1);
        REC[pp] = (unsigned)d | ((unsigned)(s & 511) << 17);
    }
}

__global__ __launch_bounds__(256) void binC(
    const unsigned* __restrict__ REC, const int* __restrict__ BB,
    int bucket_base, int Nn,
    int* __restrict__ off_out, int* __restrict__ cnt_out, int* __restrict__ AJ)
{
    __shared__ int nh[512], lo[512], fl[512], ws2[4];
    const int b = blockIdx.x, tid = threadIdx.x;
    const int gb = bucket_base + b;
    const int r0 = BB[gb], r1 = BB[gb + 1];
    const int node0 = b << 9;
    const int kmax = min(512, Nn - node0);
    nh[tid] = 0; nh[tid + 256] = 0;
    fl[tid] = 0; fl[tid + 256] = 0;
    __syncthreads();
    for (int i = r0 + tid; i < r1; i += 256)
        atomicAdd(&nh[REC[i] >> 17], 1);
    __syncthreads();
    // exclusive scan nh[512] -> lo[512]
    const int v0 = nh[2 * tid], v1 = nh[2 * tid + 1];
    const int s = v0 + v1;
    const int lane = tid & 63, wv = tid >> 6;
    int incl = s;
#pragma unroll
    for (int d = 1; d < 64; d <<= 1) {
        int up = __shfl_up(incl, d);
        if (lane >= d) incl += up;
    }
    if (lane == 63) ws2[wv] = incl;
    __syncthreads();
    if (tid == 0) {
        int run = 0;
        for (int w = 0; w < 4; ++w) { int t = ws2[w]; ws2[w] = run; run += t; }
    }
    __syncthreads();
    const int base = ws2[wv] + incl - s;
    lo[2 * tid] = base;
    lo[2 * tid + 1] = base + v0;
    __syncthreads();
    for (int k = tid; k < kmax; k += 256) {
        off_out[node0 + k] = r0 + lo[k];
        cnt_out[node0 + k] = nh[k];
    }
    for (int i = r0 + tid; i < r1; i += 256) {
        const unsigned rec = REC[i];
        const int k = rec >> 17;
        const int pos = r0 + lo[k] + atomicAdd(&fl[k], 1);
        AJ[pos] = (int)(rec & 0x1FFFFu);
    }
}

// ---- gather: Sdiv[n] = mean_e relu((RW[n]+LW[adj])*sf) ----
__global__ __launch_bounds__(256) void node_gather2(
    const int* __restrict__ off, const int* __restrict__ cnt,
    const int* __restrict__ adj,
    const u16* __restrict__ RW, const u16* __restrict__ LW,
    u16* __restrict__ Sdiv, float* __restrict__ cntf,
    const float* __restrict__ sf_p, int N)
{
    int t = blockIdx.x * 256 + threadIdx.x;
    int n = t >> 5;
    if (n >= N) return;
    int l32 = t & 31;
    int c = l32 & 15;          // 16B chunk (8 bf16) within the row
    int half = l32 >> 4;       // 0/1: edge parity
    const float sf = *sf_p;
    const int start = off[n], len = cnt[n];

    float rw[8];
    unpack8(*(const uint4*)(RW + (size_t)n * 128 + c * 8), rw);
    float acc[8] = {0.f, 0.f, 0.f, 0.f, 0.f, 0.f, 0.f, 0.f};

    for (int i = half; i < len; i += 2) {
        int l = adj[start + i];
        float lw[8];
        unpack8(*(const uint4*)(LW + (size_t)l * 128 + c * 8), lw);
#pragma unroll
        for (int j = 0; j < 8; ++j)
            acc[j] += fmaxf((rw[j] + lw[j]) * sf, 0.f);
    }
#pragma unroll
    for (int j = 0; j < 8; ++j) acc[j] += __shfl_xor(acc[j], 16);

    if (half == 0) {
        float inv = 1.f / fmaxf((float)len, 1.f);
        uint4 o;
        o.x = (unsigned)f2bf(acc[0] * inv) | ((unsigned)f2bf(acc[1] * inv) << 16);
        o.y = (unsigned)f2bf(acc[2] * inv) | ((unsigned)f2bf(acc[3] * inv) << 16);
        o.z = (unsigned)f2bf(acc[4] * inv) | ((unsigned)f2bf(acc[5] * inv) << 16);
        o.w = (unsigned)f2bf(acc[6] * inv) | ((unsigned)f2bf(acc[7] * inv) << 16);
        *(uint4*)(Sdiv + (size_t)n * 128 + c * 8) = o;
        if (l32 == 0) cntf[n] = (float)len;
    }
}

extern "C" void kernel_launch(void* const* d_in, const int* in_sizes, int n_in,
                              void* d_out, int out_size, void* d_ws, size_t ws_size,
                              hipStream_t stream)
{
    const float* pivot = (const float*)d_in[0];
    const float* child = (const float*)d_in[1];
    const int* edges = (const int*)d_in[2];
    const int F = in_sizes[3];           // 69
    const int NP = in_sizes[0] / F;
    const int NC = in_sizes[1] / F;
    const int E = in_sizes[2] / 2;
    const int* src = edges;
    const int* dst = edges + E;

    const float *pe_shift = (const float*)d_in[3], *pe_scale = (const float*)d_in[4],
                *pe_w1 = (const float*)d_in[5], *pe_b1 = (const float*)d_in[6],
                *pe_w2 = (const float*)d_in[7], *pe_b2 = (const float*)d_in[8];
    const float *ce_shift = (const float*)d_in[9], *ce_scale = (const float*)d_in[10],
                *ce_w1 = (const float*)d_in[11], *ce_b1 = (const float*)d_in[12],
                *ce_w2 = (const float*)d_in[13], *ce_b2 = (const float*)d_in[14];
    const float *vc_wl = (const float*)d_in[15], *vc_bl = (const float*)d_in[16],
                *vc_wr = (const float*)d_in[17], *vc_sf = (const float*)d_in[18],
                *vc_wf = (const float*)d_in[19], *vc_bf = (const float*)d_in[20],
                *vc_sp = (const float*)d_in[21], *vc_wo1 = (const float*)d_in[22],
                *vc_bo1 = (const float*)d_in[23], *vc_wo2 = (const float*)d_in[24],
                *vc_bo2 = (const float*)d_in[25];
    const float *cv_wl = (const float*)d_in[26], *cv_bl = (const float*)d_in[27],
                *cv_wr = (const float*)d_in[28], *cv_sf = (const float*)d_in[29],
                *cv_wf = (const float*)d_in[30], *cv_bf = (const float*)d_in[31],
                *cv_sp = (const float*)d_in[32], *cv_wo1 = (const float*)d_in[33],
                *cv_bo1 = (const float*)d_in[34], *cv_wo2 = (const float*)d_in[35],
                *cv_bo2 = (const float*)d_in[36];
    const float *out_w1 = (const float*)d_in[37], *out_b1 = (const float*)d_in[38],
                *out_w2 = (const float*)d_in[39], *out_b2 = (const float*)d_in[40];

    // ---- workspace carve (256B aligned) ----
    char* base = (char*)d_ws;
    size_t off = 0;
    auto carve = [&](size_t bytes) {
        void* p = base + off;
        off += (bytes + 255) & ~(size_t)255;
        return p;
    };
    float* Wsc = (float*)carve((size_t)4 * 16384 * 4);   // folded fp32 products
    float* Vsc = (float*)carve((size_t)4 * 128 * 4);     // folded bias vectors
    u16* WT = (u16*)carve((size_t)14 * 32768 * 2);
    u16* FP = (u16*)carve((size_t)NP * 96 * 2);
    u16* FC = (u16*)carve((size_t)NC * 96 * 2);
    u16* B0 = (u16*)carve((size_t)NP * 128 * 2);   // pv0
    u16* B1 = (u16*)carve((size_t)NC * 128 * 2);
    u16* B2 = (u16*)carve((size_t)NC * 128 * 2);
    u16* B3 = (u16*)carve((size_t)NC * 128 * 2);
    u16* B4 = (u16*)carve((size_t)NC * 128 * 2);
    const int NMAX = (NC > NP) ? NC : NP;
    float* cntf = (float*)carve((size_t)NMAX * 4);

    // counting-sort workspace
    const int NB = 120;                       // binning blocks
    const int CH = (E + NB - 1) / NB;         // edges per block chunk
    const int nbk_c = (NC + 511) >> 9;
    const int nbk_p = (NP + 511) >> 9;
    const int NBK = nbk_c + nbk_p;            // <= 1024
    int* cnt_c = (int*)carve((size_t)NC * 4);
    int* cnt_p = (int*)carve((size_t)NP * 4);
    int* off_c = (int*)carve((size_t)NC * 4);
    int* off_p = (int*)carve((size_t)NP * 4);
    int* G = (int*)carve((size_t)NBK * NB * 4);
    int* PBB = (int*)carve((size_t)NBK * NB * 4);
    int* BB = (int*)carve((size_t)(NBK + 1) * 4);
    int* Tb = (int*)carve((size_t)NBK * 4);
    unsigned* REC = (unsigned*)carve((size_t)2 * E * 4);
    int* AJ = (int*)carve((size_t)2 * E * 4);

    // ---- folded weight precompute (fp32) ----
    SmPack sp;
    sp.e[0] = {vc_wf, vc_wo1, vc_sp};            // Wfo_vc = sp*(wf@wo1t)
    sp.e[1] = {cv_wf, cv_wo1, cv_sp};            // Wfo_cv
    sp.e[2] = {vc_wo2, cv_wr, nullptr};          // Wx = vc_wo2@cv_wr
    sp.e[3] = {cv_wo2, out_w1, nullptr};         // Wh = cv_wo2@out_w1
    hipLaunchKernelGGL(smallmm, dim3(256), dim3(256), 0, stream, sp, Wsc);
    hipLaunchKernelGGL(vecpre, dim3(1), dim3(128), 0, stream,
                       vc_bf, vc_wo1, vc_sp, cv_bf, cv_wo1, cv_sp,
                       vc_bo2, cv_wr, cv_bo2, out_w1, out_b1, Vsc);
    const float* cvec_vc = Vsc;
    const float* cvec_cv = Vsc + 128;
    const float* cx = Vsc + 256;
    const float* bh = Vsc + 384;

    // ---- weight conversion ----
    WPack wp;
    auto setw = [&](int i, const float* s, int ks, int kd) {
        wp.e[i].src = s; wp.e[i].Ksrc = ks; wp.e[i].Kdst = kd;
    };
    setw(0, pe_w1, F, 96);            setw(1, pe_w2, 128, 128);
    setw(2, ce_w1, F, 96);            setw(3, ce_w2, 128, 128);
    setw(4, vc_wl, 128, 128);         setw(5, vc_wr, 128, 128);
    setw(6, Wsc + 0 * 16384, 128, 128);       // Wfo_vc
    setw(7, vc_wo1 + 128 * 128, 128, 128);    // vc wo1 bottom (ch0 part)
    setw(8, Wsc + 2 * 16384, 128, 128);       // Wx
    setw(9, cv_wl, 128, 128);         setw(10, cv_wr, 128, 128);
    setw(11, Wsc + 1 * 16384, 128, 128);      // Wfo_cv
    setw(12, cv_wo1 + 128 * 128, 128, 128);   // cv wo1 bottom (pv0 part)
    setw(13, Wsc + 3 * 16384, 128, 128);      // Wh
    hipLaunchKernelGGL(wconvert, dim3(14 * 128), dim3(256), 0, stream, wp, WT);
    auto wt = [&](int i) { return WT + (size_t)i * 32768; };

    // ---- feature conversion ----
    hipLaunchKernelGGL(featconv, dim3(2048), dim3(256), 0, stream,
                       pivot, pe_shift, pe_scale, FP, (long)NP * 96, F);
    hipLaunchKernelGGL(featconv, dim3(2048), dim3(256), 0, stream,
                       child, ce_shift, ce_scale, FC, (long)NC * 96, F);

    // ---- CSR via counting sort ----
    hipMemsetAsync(Tb, 0, (size_t)NBK * 4, stream);
    hipLaunchKernelGGL(binA, dim3(NB), dim3(256), 0, stream,
                       src, dst, E, CH, NB, nbk_c, NBK, G, Tb);
    hipLaunchKernelGGL(binS, dim3(1), dim3(512), 0, stream, Tb, NBK, BB);
    hipLaunchKernelGGL(binP, dim3(NBK), dim3(64), 0, stream, G, BB, NB, PBB);
    hipLaunchKernelGGL(binB, dim3(NB), dim3(256), 0, stream,
                       src, dst, E, CH, NB, nbk_c, NBK, PBB, REC);
    hipLaunchKernelGGL(binC, dim3(nbk_c), dim3(256), 0, stream,
                       REC, BB, 0, NC, off_c, cnt_c, AJ);
    hipLaunchKernelGGL(binC, dim3(nbk_p), dim3(256), 0, stream,
                       REC, BB, nbk_c, NP, off_p, cnt_p, AJ);

    // ---- GEMM pipeline ----
    const dim3 blk(256);
    auto grd = [](int M) {
        int items = M >> 4;
        int b = (items + 3) / 4;
        return dim3((unsigned)(b < 512 ? b : 512));
    };

    // embeddings
    gemm_rb<3, false, true, false><<<grd(NP), blk, 0, stream>>>(
        FP, nullptr, wt(0), nullptr, pe_b1, nullptr, nullptr, B1, NP);
    gemm_rb<4, false, true, false><<<grd(NP), blk, 0, stream>>>(
        B1, nullptr, wt(1), nullptr, pe_b2, nullptr, nullptr, B0, NP);   // pv0
    gemm_rb<3, false, true, false><<<grd(NC), blk, 0, stream>>>(
        FC, nullptr, wt(2), nullptr, ce_b1, nullptr, nullptr, B1, NC);
    gemm_rb<4, false, true, false><<<grd(NC), blk, 0, stream>>>(
        B1, nullptr, wt(3), nullptr, ce_b2, nullptr, nullptr, B2, NC);   // ch0

    // conv v->c (aggregate to children)
    gemm_rb<4, false, false, false><<<grd(NC), blk, 0, stream>>>(
        B2, nullptr, wt(4), nullptr, vc_bl, nullptr, nullptr, B1, NC);   // RW_c
    gemm_rb<4, false, false, false><<<grd(NP), blk, 0, stream>>>(
        B0, nullptr, wt(5), nullptr, nullptr, nullptr, nullptr, B3, NP); // LW_v
    hipLaunchKernelGGL(node_gather2, dim3(((size_t)NC * 32 + 255) / 256), blk, 0,
                       stream, off_c, cnt_c, AJ, B1, B3, B4, cntf, vc_sf, NC);
    // h_c = relu(Sdiv@Wfo_vc + ch0@wo1b + bo1 + gate*cvec)
    gemm_rb<4, true, true, true><<<grd(NC), blk, 0, stream>>>(
        B4, B2, wt(6), wt(7), vc_bo1, cvec_vc, cntf, B1, NC);            // h_c
    gemm_rb<4, false, false, false><<<grd(NC), blk, 0, stream>>>(
        B1, nullptr, wt(8), nullptr, cx, nullptr, nullptr, B3, NC);      // LW_c

    // conv c->v (aggregate to pivot)
    gemm_rb<4, false, false, false><<<grd(NP), blk, 0, stream>>>(
        B0, nullptr, wt(9), nullptr, cv_bl, nullptr, nullptr, B2, NP);   // RW_p
    hipLaunchKernelGGL(node_gather2, dim3(((size_t)NP * 32 + 255) / 256), blk, 0,
                       stream, off_p, cnt_p, AJ, B2, B3, B4, cntf, cv_sf, NP);
    // h_p = relu(Sdiv@Wfo_cv + pv0@wo1b + bo1 + gate*cvec)
    gemm_rb<4, true, true, true><<<grd(NP), blk, 0, stream>>>(
        B4, B0, wt(11), wt(12), cv_bo1, cvec_cv, cntf, B1, NP);          // h_p

    // fused head on h_p with folded W1'=Wh, b1'=bh
    hipLaunchKernelGGL(head_fused, grd(NP), blk, 0, stream,
                       B1, wt(13), bh, out_w2, out_b2, (float*)d_out, NP);
}